// Round 11
// baseline (448.150 us; speedup 1.0000x reference)
//
#include <hip/hip_runtime.h>
#include <stdint.h>

typedef __bf16 bf16x8 __attribute__((ext_vector_type(8)));
typedef float f32x4 __attribute__((ext_vector_type(4)));
typedef unsigned short u16;
typedef uint32_t u32;

union V16 { uint4 v; u16 e[8]; };

__device__ __forceinline__ float bf2f(u16 h) {
    u32 u = ((u32)h) << 16; float f; __builtin_memcpy(&f, &u, 4); return f;
}
__device__ __forceinline__ u16 f2bf(float f) {
    u32 u; __builtin_memcpy(&u, &f, 4);
    u32 r = (u + 0x7FFFu + ((u >> 16) & 1u)) >> 16; return (u16)r;
}
__device__ __forceinline__ u32 cvtpk(float lo, float hi) {
    u32 r;
    asm("v_cvt_pk_bf16_f32 %0, %1, %2" : "=v"(r) : "v"(lo), "v"(hi));
    return r;
}
__device__ __forceinline__ f32x4 mfma16(bf16x8 a, bf16x8 b, f32x4 c) {
    return __builtin_amdgcn_mfma_f32_16x16x32_bf16(a, b, c, 0, 0, 0);
}
// async 16B global -> LDS (wave-uniform LDS base; HW adds lane*16)
__device__ __forceinline__ void gll16(const u16* g, u16* l) {
    __builtin_amdgcn_global_load_lds(
        (const __attribute__((address_space(1))) unsigned int*)g,
        (__attribute__((address_space(3))) unsigned int*)l, 16, 0, 0);
}
// flag: 0=bf16, 1=f32, 2=f64
__device__ __forceinline__ float loadElem(const void* p, size_t i, int fl) {
    if (fl == 1) return ((const float*)p)[i];
    if (fl == 2) return (float)((const double*)p)[i];
    return bf2f(((const u16*)p)[i]);
}

// ---------------- dtype detect on x ----------------
__global__ __launch_bounds__(256) void k_detect(const u32* __restrict__ xw, int* __restrict__ flag) {
    int t = threadIdx.x;
    int cA = 0, cB = 0;
    #pragma unroll
    for (int i = 0; i < 16; i++) {
        u32 w = xw[i * 256 + t];
        cA += (((w >> 23) & 0xFFu) >= 0xC0u) ? 1 : 0;
        cB += (((w >> 7)  & 0xFFu) >= 0xC0u) ? 1 : 0;
    }
    #pragma unroll
    for (int m = 32; m >= 1; m >>= 1) { cA += __shfl_xor(cA, m); cB += __shfl_xor(cB, m); }
    __shared__ int sA[4], sB[4];
    if ((t & 63) == 0) { sA[t >> 6] = cA; sB[t >> 6] = cB; }
    __syncthreads();
    if (t == 0) {
        int a = sA[0] + sA[1] + sA[2] + sA[3];
        int b = sB[0] + sB[1] + sB[2] + sB[3];
        *flag = (a > 64) ? 2 : ((b > 64) ? 1 : 0);
    }
}

// ---------------- mean over HW: xg[b*512+c] ----------------
__global__ __launch_bounds__(256) void k_mean(const void* __restrict__ xv, const int* __restrict__ dt,
                                              float* __restrict__ xg) {
    int bc = blockIdx.x;
    int t = threadIdx.x;
    int fl = *dt;
    const size_t base = (size_t)bc * 4096;
    float s = 0.f;
    if (fl == 1) {
        const float* p = (const float*)xv + base;
        #pragma unroll
        for (int i = 0; i < 4; i++) {
            float4 v = *reinterpret_cast<const float4*>(p + (size_t)(i * 256 + t) * 4);
            s += v.x + v.y + v.z + v.w;
        }
    } else {
        for (int i = 0; i < 16; i++) s += loadElem(xv, base + i * 256 + t, fl);
    }
    #pragma unroll
    for (int m = 32; m >= 1; m >>= 1) s += __shfl_xor(s, m);
    __shared__ float wsum[4];
    if ((t & 63) == 0) wsum[t >> 6] = s;
    __syncthreads();
    if (t == 0) xg[bc] = (wsum[0] + wsum[1] + wsum[2] + wsum[3]) * (1.f / 4096.f);
}

// ---------------- transpose(+cast) x [B][512][4096] -> xT bf16 [B][4096][512] ----------------
__global__ __launch_bounds__(256) void k_xpose(const void* __restrict__ xv, const int* __restrict__ dt,
                                               u16* __restrict__ xT) {
    __shared__ u16 tile[64][72];
    int b = blockIdx.z;
    int n0 = blockIdx.x * 64, c0 = blockIdx.y * 64;
    u16* xTb = xT + (size_t)b * 4096 * 512;
    int t = threadIdx.x;
    int fl = *dt;
    const size_t xbase = (size_t)b * 512 * 4096;
    if (fl == 1) {
        const float* xb = (const float*)xv + xbase;
        int cr = t >> 4, n4 = (t & 15) * 4;
        #pragma unroll
        for (int i = 0; i < 4; i++) {
            int c = cr + i * 16;
            float4 v = *reinterpret_cast<const float4*>(xb + (size_t)(c0 + c) * 4096 + n0 + n4);
            tile[n4 + 0][c] = f2bf(v.x); tile[n4 + 1][c] = f2bf(v.y);
            tile[n4 + 2][c] = f2bf(v.z); tile[n4 + 3][c] = f2bf(v.w);
        }
    } else {
        int c4 = t >> 6, n = t & 63;
        for (int i = 0; i < 16; i++) {
            int c = c4 + i * 4;
            tile[n][c] = f2bf(loadElem(xv, xbase + (size_t)(c0 + c) * 4096 + n0 + n, fl));
        }
    }
    __syncthreads();
    int nr = t >> 3, c8 = (t & 7) * 8;
    #pragma unroll
    for (int i = 0; i < 2; i++) {
        int n = nr + i * 32;
        V16 v;
        #pragma unroll
        for (int j = 0; j < 8; j++) v.e[j] = tile[n][c8 + j];
        *reinterpret_cast<uint4*>(xTb + (size_t)(n0 + n) * 512 + c0 + c8) = v.v;
    }
}

// ---------------- fold mean through kW1/vW cols [0,512): per-(b,o) f32 bias ----------------
__global__ __launch_bounds__(64) void k_consts(const void* __restrict__ kW1, const void* __restrict__ vW,
                                               const int* __restrict__ dt, const float* __restrict__ xg,
                                               float* __restrict__ ck, float* __restrict__ cv) {
    int bo = blockIdx.x; int b = bo >> 8; int o = bo & 255;
    int l = threadIdx.x;
    int fl = *dt;
    const float* g = xg + b * 512;
    float sk = 0.f, sv = 0.f;
    for (int c = l; c < 512; c += 64) {
        float xv = g[c];
        sk += loadElem(kW1, (size_t)o * 1024 + c, fl) * xv;
        sv += loadElem(vW,  (size_t)o * 1024 + c, fl) * xv;
    }
    #pragma unroll
    for (int m = 32; m >= 1; m >>= 1) { sk += __shfl_xor(sk, m); sv += __shfl_xor(sv, m); }
    if (l == 0) { ck[bo] = sk; cv[bo] = sv; }
}

// ---------------- weights -> bf16 into ws ----------------
__global__ __launch_bounds__(256) void k_wconv(const void* __restrict__ qW1, const void* __restrict__ qW2,
                                               const void* __restrict__ kW1, const void* __restrict__ kW2,
                                               const void* __restrict__ vW, const void* __restrict__ oW,
                                               const int* __restrict__ dt, u16* __restrict__ dst) {
    int i = blockIdx.x * 256 + threadIdx.x;
    int fl = *dt;
    const void* s; size_t so;
    if (i < 131072)      { s = qW1; so = (size_t)i; }
    else if (i < 196608) { int j = i - 131072; s = qW2; so = (size_t)j; }
    else if (i < 327680) { int j = i - 196608; s = kW1; so = (size_t)(j >> 9) * 1024 + 512 + (j & 511); }
    else if (i < 393216) { int j = i - 327680; s = kW2; so = (size_t)j; }
    else if (i < 524288) { int j = i - 393216; s = vW;  so = (size_t)(j >> 9) * 1024 + 512 + (j & 511); }
    else                 { int j = i - 524288; s = oW;  so = (size_t)j; }
    dst[i] = f2bf(loadElem(s, so, fl));
}

// ---------------- affine params -> f32 into ws ----------------
__global__ __launch_bounds__(256) void k_pconv(const void* qg1, const void* qb1, const void* qg2, const void* qb2,
                                               const void* kg1, const void* kb1, const void* kg2, const void* kb2,
                                               const void* vg, const void* vb, const void* og, const void* ob,
                                               const int* __restrict__ dt, float* __restrict__ pg) {
    int j = blockIdx.x * 256 + threadIdx.x;
    if (j >= 3584) return;
    int fl = *dt;
    const void* s; int o;
    if (j < 256)       { s = qg1; o = j; }
    else if (j < 512)  { s = qb1; o = j - 256; }
    else if (j < 768)  { s = qg2; o = j - 512; }
    else if (j < 1024) { s = qb2; o = j - 768; }
    else if (j < 1280) { s = kg1; o = j - 1024; }
    else if (j < 1536) { s = kb1; o = j - 1280; }
    else if (j < 1792) { s = kg2; o = j - 1536; }
    else if (j < 2048) { s = kb2; o = j - 1792; }
    else if (j < 2304) { s = vg;  o = j - 2048; }
    else if (j < 2560) { s = vb;  o = j - 2304; }
    else if (j < 3072) { s = og;  o = j - 2560; }
    else               { s = ob;  o = j - 3072; }
    pg[j] = loadElem(s, (size_t)o, fl);
}

// ---------------- gemm_bt ----------------
template<bool AFF_ROW, typename OT>
__global__ __launch_bounds__(256) void k_gemm_bt(
    const u16* __restrict__ A, long aBS, int lda,
    const u16* __restrict__ Bm, long bBS, int ldb,
    OT* __restrict__ C, long cBS, int ldc,
    const float* __restrict__ gamma, const float* __restrict__ beta,
    const float* __restrict__ bias, int biasBS, int K) {
    __shared__ u16 As[128 * 64];
    __shared__ u16 Bs[128 * 64];
    int b = blockIdx.z;
    const u16* Ab = A + (size_t)b * aBS;
    const u16* Bb = Bm + (size_t)b * bBS;
    OT* Cb = C + (size_t)b * cBS;
    int m0 = blockIdx.x * 128, n0 = blockIdx.y * 128;
    int t = threadIdx.x;
    int lane = t & 63, wid = t >> 6;
    int wr = wid >> 1, wc = wid & 1;
    int li = lane & 15, lk = lane >> 4;

    f32x4 acc[4][4] = {};

    for (int k0 = 0; k0 < K; k0 += 64) {
        #pragma unroll
        for (int i = 0; i < 4; i++) {
            int e = (i * 256 + t) * 8;
            int r = e >> 6, c = e & 63;
            u32 off = ((u32)(r * 128 + c * 2)) ^ (((u32)(r & 7)) << 4);
            uint4 va = *reinterpret_cast<const uint4*>(Ab + (size_t)(m0 + r) * lda + k0 + c);
            *reinterpret_cast<uint4*>(reinterpret_cast<char*>(As) + off) = va;
            uint4 vb = *reinterpret_cast<const uint4*>(Bb + (size_t)(n0 + r) * ldb + k0 + c);
            *reinterpret_cast<uint4*>(reinterpret_cast<char*>(Bs) + off) = vb;
        }
        __syncthreads();
        #pragma unroll
        for (int ks = 0; ks < 2; ks++) {
            bf16x8 af[4], bfr[4];
            #pragma unroll
            for (int mi = 0; mi < 4; mi++) {
                int r = wr * 64 + mi * 16 + li;
                u32 off = ((u32)(r * 128 + (ks * 32 + lk * 8) * 2)) ^ (((u32)(r & 7)) << 4);
                af[mi] = *reinterpret_cast<const bf16x8*>(reinterpret_cast<const char*>(As) + off);
            }
            #pragma unroll
            for (int ni = 0; ni < 4; ni++) {
                int r = wc * 64 + ni * 16 + li;
                u32 off = ((u32)(r * 128 + (ks * 32 + lk * 8) * 2)) ^ (((u32)(r & 7)) << 4);
                bfr[ni] = *reinterpret_cast<const bf16x8*>(reinterpret_cast<const char*>(Bs) + off);
            }
            #pragma unroll
            for (int mi = 0; mi < 4; mi++)
                #pragma unroll
                for (int ni = 0; ni < 4; ni++)
                    acc[mi][ni] = mfma16(af[mi], bfr[ni], acc[mi][ni]);
        }
        __syncthreads();
    }
    #pragma unroll
    for (int mi = 0; mi < 4; mi++) {
        #pragma unroll
        for (int ni = 0; ni < 4; ni++) {
            #pragma unroll
            for (int r = 0; r < 4; r++) {
                int m = m0 + wr * 64 + mi * 16 + lk * 4 + r;
                int n = n0 + wc * 64 + ni * 16 + li;
                int oc = AFF_ROW ? m : n;
                float v = acc[mi][ni][r];
                if (bias) v += bias[b * biasBS + oc];
                float y = v * gamma[oc] + beta[oc];
                y = fmaxf(y, 0.f);
                if constexpr (sizeof(OT) == 2) Cb[(size_t)m * ldc + n] = f2bf(y);
                else                           Cb[(size_t)m * ldc + n] = y;
            }
        }
    }
}

// ---------------- flash attention v5: swapped QK^T + async dbuf + deferred-L + cvt_pk ----------------
__global__ __launch_bounds__(256, 2) void k_attn(const u16* __restrict__ Q, const u16* __restrict__ Kt,
                                                 const u16* __restrict__ V, u16* __restrict__ Op,
                                                 float2* __restrict__ ML) {
    __shared__ u16 Ks[2][32 * 256];
    __shared__ u16 Vs[2][256 * 32];
    __shared__ u16 Ps[128 * 32];
    char* PsB = (char*)Ps;
    int wg = blockIdx.x;
    int bs = wg & 15, qt = wg >> 4;
    int b = bs >> 2, sp = bs & 3;
    int n0 = qt * 128;
    int k0 = sp * 1024;
    const size_t S = (size_t)4096 * 256;
    const u16* Qb = Q + (size_t)b * S + (size_t)n0 * 256;
    const u16* Kb = Kt + (size_t)b * S + (size_t)k0 * 256;
    const u16* Vb = V + (size_t)b * S + k0;      // channel-major [256][4096]
    int t = threadIdx.x;
    int lane = t & 63, wid = t >> 6;
    int li = lane & 15, lk = lane >> 4;
    int qw = wid * 32;

    // Q B-fragments (query = fq*16+li, d-chunk = kc*32+lk*8)
    bf16x8 qf[2][8];
    #pragma unroll
    for (int fq = 0; fq < 2; fq++)
        #pragma unroll
        for (int kc = 0; kc < 8; kc++)
            qf[fq][kc] = *reinterpret_cast<const bf16x8*>(Qb + (size_t)(qw + fq * 16 + li) * 256 + kc * 32 + lk * 8);

    f32x4 acc[2][16] = {};
    float M[2] = {-1e30f, -1e30f}, L[2] = {0.f, 0.f};   // L = per-lane partial (own 8 keys); reduced at end
    const float SCL = 0.0625f * 1.44269504088896f;

    auto stageTo = [&](int kt, u16* Kd, u16* Vd) {
        const u16* Kp = Kb + (size_t)kt * 32 * 256;
        const u16* Vp = Vb + kt * 32;
        #pragma unroll
        for (int j = 0; j < 4; j++) {
            int c = wid * 4 + j;
            u32 pl = (u32)c * 1024 + (u32)lane * 16;      // linear byte pos in tile
            u32 krow = pl >> 9;
            u32 kq = (pl & 511) ^ ((krow & 7) << 4);       // inverse of read swizzle
            gll16(Kp + krow * 256 + (kq >> 1), Kd + (c << 9));
            u32 vcc = pl >> 6;
            u32 vq = (pl & 63) ^ (((vcc >> 1) & 3) << 4);  // inverse of read swizzle
            gll16(Vp + (size_t)vcc * 4096 + (vq >> 1), Vd + (c << 9));
        }
    };

    auto body = [&](int kt, const char* KsB, const char* VsB, u16* KdN, u16* VdN) {
        if (kt + 1 < 32) {
            stageTo(kt + 1, KdN, VdN);
            asm volatile("s_waitcnt vmcnt(8)" ::: "memory");   // tile kt landed; kt+1 in flight
        } else {
            asm volatile("s_waitcnt vmcnt(0)" ::: "memory");
        }
        __builtin_amdgcn_sched_barrier(0);
        __builtin_amdgcn_s_barrier();

        // S^T = K · Q : sf[mk][fq], key = mk*16+lk*4+r, query = fq*16+li
        __builtin_amdgcn_s_setprio(1);
        f32x4 sf[2][2] = {};
        #pragma unroll
        for (int mk = 0; mk < 2; mk++) {
            #pragma unroll
            for (int kc = 0; kc < 8; kc++) {
                int row = mk * 16 + li;
                u32 off = (u32)(row * 512) + (((u32)(kc * 64 + lk * 16)) ^ (((u32)(row & 7)) << 4));
                bf16x8 kb = *reinterpret_cast<const bf16x8*>(KsB + off);
                sf[mk][0] = mfma16(kb, qf[0][kc], sf[mk][0]);
                sf[mk][1] = mfma16(kb, qf[1][kc], sf[mk][1]);
            }
        }
        __builtin_amdgcn_s_setprio(0);

        // online softmax: max via 2 shuffles/fq; L kept as per-lane partial (no sum shuffles)
        float pm[2];
        #pragma unroll
        for (int fq = 0; fq < 2; fq++) {
            float mx = fmaxf(fmaxf(fmaxf(sf[0][fq][0], sf[0][fq][1]), fmaxf(sf[0][fq][2], sf[0][fq][3])),
                             fmaxf(fmaxf(sf[1][fq][0], sf[1][fq][1]), fmaxf(sf[1][fq][2], sf[1][fq][3])));
            mx = fmaxf(mx, __shfl_xor(mx, 16));
            mx = fmaxf(mx, __shfl_xor(mx, 32));
            pm[fq] = mx * SCL;
        }
        bool ok = (pm[0] <= M[0] + 8.f) && (pm[1] <= M[1] + 8.f);
        if (!__all(ok ? 1 : 0)) {
            #pragma unroll
            for (int fq = 0; fq < 2; fq++) {
                float nM = fmaxf(M[fq], pm[fq]);
                float rs = exp2f(M[fq] - nM);
                L[fq] *= rs; M[fq] = nM;
                #pragma unroll
                for (int ct = 0; ct < 16; ct++) {
                    acc[fq][ct][0] *= rs; acc[fq][ct][1] *= rs;
                    acc[fq][ct][2] *= rs; acc[fq][ct][3] *= rs;
                }
            }
        }
        #pragma unroll
        for (int fq = 0; fq < 2; fq++) {
            int row = qw + fq * 16 + li;
            float lloc = 0.f;
            #pragma unroll
            for (int mk = 0; mk < 2; mk++) {
                float p0 = exp2f(sf[mk][fq][0] * SCL - M[fq]);
                float p1 = exp2f(sf[mk][fq][1] * SCL - M[fq]);
                float p2 = exp2f(sf[mk][fq][2] * SCL - M[fq]);
                float p3 = exp2f(sf[mk][fq][3] * SCL - M[fq]);
                lloc += (p0 + p1) + (p2 + p3);
                uint2 pw; pw.x = cvtpk(p0, p1); pw.y = cvtpk(p2, p3);
                u32 off = ((u32)(row * 64 + mk * 32 + lk * 8)) ^ (((u32)(row & 7)) << 4);
                *reinterpret_cast<uint2*>(PsB + off) = pw;
            }
            L[fq] += lloc;
        }

        // O^T += V^T · P^T  (Ps rows wave-private)
        __builtin_amdgcn_s_setprio(1);
        {
            bf16x8 pb[2];
            #pragma unroll
            for (int fq = 0; fq < 2; fq++) {
                int row = qw + fq * 16 + li;
                u32 off = ((u32)(row * 64 + lk * 16)) ^ (((u32)(row & 7)) << 4);
                pb[fq] = *reinterpret_cast<const bf16x8*>(PsB + off);
            }
            #pragma unroll
            for (int ct = 0; ct < 16; ct++) {
                int vr = ct * 16 + li;
                u32 voff = (u32)(vr * 64) + (((u32)(lk * 16)) ^ (((u32)((vr >> 1) & 3)) << 4));
                bf16x8 va = *reinterpret_cast<const bf16x8*>(VsB + voff);
                acc[0][ct] = mfma16(va, pb[0], acc[0][ct]);
                acc[1][ct] = mfma16(va, pb[1], acc[1][ct]);
            }
        }
        __builtin_amdgcn_s_setprio(0);
        asm volatile("s_waitcnt lgkmcnt(0)" ::: "memory");
        __builtin_amdgcn_s_barrier();   // all waves done reading this buf; next gll may overwrite
    };

    stageTo(0, &Ks[0][0], &Vs[0][0]);

    for (int it = 0; it < 32; it += 2) {
        body(it,     (const char*)&Ks[0][0], (const char*)&Vs[0][0], &Ks[1][0], &Vs[1][0]);
        body(it + 1, (const char*)&Ks[1][0], (const char*)&Vs[1][0], &Ks[0][0], &Vs[0][0]);
    }

    // reduce deferred per-lane L across the 4 lk groups (butterfly -> total in all lanes)
    #pragma unroll
    for (int fq = 0; fq < 2; fq++) {
        L[fq] += __shfl_xor(L[fq], 16);
        L[fq] += __shfl_xor(L[fq], 32);
    }

    // epilogue: unnormalized partials (query per lane-col, channels packed 4-wide)
    size_t obase = (size_t)(sp * 4 + b) * 4096 + n0;
    #pragma unroll
    for (int fq = 0; fq < 2; fq++) {
        int q = qw + fq * 16 + li;
        #pragma unroll
        for (int ct = 0; ct < 16; ct++) {
            uint2 ow;
            ow.x = cvtpk(acc[fq][ct][0], acc[fq][ct][1]);
            ow.y = cvtpk(acc[fq][ct][2], acc[fq][ct][3]);
            *reinterpret_cast<uint2*>(&Op[(obase + q) * 256 + ct * 16 + lk * 4]) = ow;
        }
    }
    if (lk == 0) {
        #pragma unroll
        for (int fq = 0; fq < 2; fq++) {
            float2 v; v.x = M[fq]; v.y = L[fq];
            ML[obase + qw + fq * 16 + li] = v;
        }
    }
}

// ---------------- merge split-KV partials -> ctx bf16 [b][4096][256] ----------------
__global__ __launch_bounds__(256) void k_merge(const u16* __restrict__ Op, const float2* __restrict__ ML,
                                               u16* __restrict__ ctx) {
    int wg = blockIdx.x;               // 16384 = 4b x 4096q
    int t = threadIdx.x;               // ch
    int b = wg >> 12, q = wg & 4095;
    float2 ml[4];
    float Mx = -1e30f;
    #pragma unroll
    for (int s = 0; s < 4; s++) { ml[s] = ML[((size_t)(s * 4 + b) << 12) + q]; Mx = fmaxf(Mx, ml[s].x); }
    float Lt = 0.f, w[4];
    #pragma unroll
    for (int s = 0; s < 4; s++) { w[s] = exp2f(ml[s].x - Mx); Lt += ml[s].y * w[s]; }
    float inv = 1.f / Lt;
    float o = 0.f;
    #pragma unroll
    for (int s = 0; s < 4; s++)
        o += w[s] * bf2f(Op[((((size_t)(s * 4 + b) << 12) + q)) * 256 + t]);
    ctx[(((size_t)b << 12) + q) * 256 + t] = f2bf(o * inv);
}

extern "C" void kernel_launch(void* const* d_in, const int* in_sizes, int n_in,
                              void* d_out, int out_size, void* d_ws, size_t ws_size,
                              hipStream_t stream) {
    const void* x   = d_in[0];
    const void* qW1 = d_in[1];  const void* qg1 = d_in[2];  const void* qb1 = d_in[3];
    const void* qW2 = d_in[4];  const void* qg2 = d_in[5];  const void* qb2 = d_in[6];
    const void* kW1 = d_in[7];  const void* kg1 = d_in[8];  const void* kb1 = d_in[9];
    const void* kW2 = d_in[10]; const void* kg2 = d_in[11]; const void* kb2 = d_in[12];
    const void* vW  = d_in[13]; const void* vg  = d_in[14]; const void* vb  = d_in[15];
    const void* oW  = d_in[16]; const void* og  = d_in[17]; const void* ob  = d_in[18];

    char* ws = (char*)d_ws;
    int*   dflag = (int*)ws;
    float* xg = (float*)(ws + 4096);
    float* ck = (float*)(ws + 16384);
    float* cv = (float*)(ws + 20480);
    float* pg = (float*)(ws + 24576);
    u16* wb = (u16*)(ws + 40960);              // 655360 bf16 weights, ends at byte 1,351,680
    u16* qW1b = wb;
    u16* qW2b = wb + 131072;
    u16* kW1b = wb + 196608;
    u16* kW2b = wb + 327680;
    u16* vWb  = wb + 393216;
    u16* oWb  = wb + 524288;
    const size_t S = (size_t)4096 * 256;
    const size_t SLOT = 4 * S;
    u16* s0 = (u16*)(ws + 0x180000);           // slots start at 1.5 MiB (clear of wb)
    u16* s1 = s0 + SLOT;
    u16* s2 = s1 + SLOT;
    u16* s3 = s2 + SLOT;
    float2* mlBuf = (float2*)s3;               // ML lives in s3 (free during attn)
    u16* xT = (u16*)d_out;                     // bf16 scratch in d_out; dead before attn
    u16* opart = (u16*)d_out;                  // attn partials [16][4096][256] bf16 = full d_out
    u16* ctxBuf = s1;                          // ctx into s1 (Q dead after attn)

    k_detect<<<1, 256, 0, stream>>>((const u32*)x, dflag);
    k_mean<<<2048, 256, 0, stream>>>(x, dflag, xg);
    k_xpose<<<dim3(64, 8, 4), 256, 0, stream>>>(x, dflag, xT);
    k_consts<<<1024, 64, 0, stream>>>(kW1, vW, dflag, xg, ck, cv);
    k_wconv<<<2560, 256, 0, stream>>>(qW1, qW2, kW1, kW2, vW, oW, dflag, wb);
    k_pconv<<<14, 256, 0, stream>>>(qg1, qb1, qg2, qb2, kg1, kb1, kg2, kb2,
                                    vg, vb, og, ob, dflag, pg);

    const long XS = (long)4096 * 512;
    // q1 -> s0
    k_gemm_bt<false, u16><<<dim3(32, 2, 4), 256, 0, stream>>>(xT, XS, 512, qW1b, 0, 512,
        s0, (long)S, 256, pg + 0, pg + 256, nullptr, 0, 512);
    // q2 -> s1
    k_gemm_bt<false, u16><<<dim3(32, 2, 4), 256, 0, stream>>>(s0, (long)S, 256, qW2b, 0, 256,
        s1, (long)S, 256, pg + 512, pg + 768, nullptr, 0, 256);
    // k1 (folded-mean bias ck) -> s0
    k_gemm_bt<false, u16><<<dim3(32, 2, 4), 256, 0, stream>>>(xT, XS, 512, kW1b, 0, 512,
        s0, (long)S, 256, pg + 1024, pg + 1280, ck, 256, 512);
    // k2 -> s2
    k_gemm_bt<false, u16><<<dim3(32, 2, 4), 256, 0, stream>>>(s0, (long)S, 256, kW2b, 0, 256,
        s2, (long)S, 256, pg + 1536, pg + 1792, nullptr, 0, 256);
    // v (channel-major, bias cv) -> s0
    k_gemm_bt<true, u16><<<dim3(2, 32, 4), 256, 0, stream>>>(vWb, 0, 512, xT, XS, 512,
        s0, (long)S, 4096, pg + 2048, pg + 2304, cv, 256, 512);
    // attention (split-KV x4): Q(s1), K(s2), V(s0) -> partials in d_out, ML in s3
    k_attn<<<512, 256, 0, stream>>>(s1, s2, s0, opart, mlBuf);
    // merge -> ctx (s1; Q dead)
    k_merge<<<16384, 256, 0, stream>>>(opart, mlBuf, ctxBuf);
    // out projection -> d_out as f32 [B][512][4096]
    k_gemm_bt<true, float><<<dim3(4, 32, 4), 256, 0, stream>>>(oWb, 0, 256, ctxBuf, (long)S, 256,
        (float*)d_out, (long)512 * 4096, 4096, pg + 2560, pg + 3072, nullptr, 0, 256);
}

// Round 12
// 262.356 us; speedup vs baseline: 1.7082x; 1.7082x over previous
//
#include <hip/hip_runtime.h>
#include <stdint.h>

typedef __bf16 bf16x8 __attribute__((ext_vector_type(8)));
typedef float f32x4 __attribute__((ext_vector_type(4)));
typedef unsigned short u16;
typedef uint32_t u32;

union V16 { uint4 v; u16 e[8]; };

__device__ __forceinline__ float bf2f(u16 h) {
    u32 u = ((u32)h) << 16; float f; __builtin_memcpy(&f, &u, 4); return f;
}
__device__ __forceinline__ u16 f2bf(float f) {
    u32 u; __builtin_memcpy(&u, &f, 4);
    u32 r = (u + 0x7FFFu + ((u >> 16) & 1u)) >> 16; return (u16)r;
}
__device__ __forceinline__ u32 pack2(float a, float b) {
    return (u32)f2bf(a) | ((u32)f2bf(b) << 16);
}
__device__ __forceinline__ f32x4 mfma16(bf16x8 a, bf16x8 b, f32x4 c) {
    return __builtin_amdgcn_mfma_f32_16x16x32_bf16(a, b, c, 0, 0, 0);
}
// async 16B global -> LDS (wave-uniform LDS base; HW adds lane*16)
__device__ __forceinline__ void gll16(const u16* g, u16* l) {
    __builtin_amdgcn_global_load_lds(
        (const __attribute__((address_space(1))) unsigned int*)g,
        (__attribute__((address_space(3))) unsigned int*)l, 16, 0, 0);
}
// flag: 0=bf16, 1=f32, 2=f64
__device__ __forceinline__ float loadElem(const void* p, size_t i, int fl) {
    if (fl == 1) return ((const float*)p)[i];
    if (fl == 2) return (float)((const double*)p)[i];
    return bf2f(((const u16*)p)[i]);
}

// ---------------- dtype detect on x ----------------
__global__ __launch_bounds__(256) void k_detect(const u32* __restrict__ xw, int* __restrict__ flag) {
    int t = threadIdx.x;
    int cA = 0, cB = 0;
    #pragma unroll
    for (int i = 0; i < 16; i++) {
        u32 w = xw[i * 256 + t];
        cA += (((w >> 23) & 0xFFu) >= 0xC0u) ? 1 : 0;
        cB += (((w >> 7)  & 0xFFu) >= 0xC0u) ? 1 : 0;
    }
    #pragma unroll
    for (int m = 32; m >= 1; m >>= 1) { cA += __shfl_xor(cA, m); cB += __shfl_xor(cB, m); }
    __shared__ int sA[4], sB[4];
    if ((t & 63) == 0) { sA[t >> 6] = cA; sB[t >> 6] = cB; }
    __syncthreads();
    if (t == 0) {
        int a = sA[0] + sA[1] + sA[2] + sA[3];
        int b = sB[0] + sB[1] + sB[2] + sB[3];
        *flag = (a > 64) ? 2 : ((b > 64) ? 1 : 0);
    }
}

// ---------------- mean over HW: xg[b*512+c] ----------------
__global__ __launch_bounds__(256) void k_mean(const void* __restrict__ xv, const int* __restrict__ dt,
                                              float* __restrict__ xg) {
    int bc = blockIdx.x;
    int t = threadIdx.x;
    int fl = *dt;
    const size_t base = (size_t)bc * 4096;
    float s = 0.f;
    if (fl == 1) {
        const float* p = (const float*)xv + base;
        #pragma unroll
        for (int i = 0; i < 4; i++) {
            float4 v = *reinterpret_cast<const float4*>(p + (size_t)(i * 256 + t) * 4);
            s += v.x + v.y + v.z + v.w;
        }
    } else {
        for (int i = 0; i < 16; i++) s += loadElem(xv, base + i * 256 + t, fl);
    }
    #pragma unroll
    for (int m = 32; m >= 1; m >>= 1) s += __shfl_xor(s, m);
    __shared__ float wsum[4];
    if ((t & 63) == 0) wsum[t >> 6] = s;
    __syncthreads();
    if (t == 0) xg[bc] = (wsum[0] + wsum[1] + wsum[2] + wsum[3]) * (1.f / 4096.f);
}

// ---------------- transpose(+cast) x [B][512][4096] -> xT bf16 [B][4096][512] ----------------
__global__ __launch_bounds__(256) void k_xpose(const void* __restrict__ xv, const int* __restrict__ dt,
                                               u16* __restrict__ xT) {
    __shared__ u16 tile[64][72];
    int b = blockIdx.z;
    int n0 = blockIdx.x * 64, c0 = blockIdx.y * 64;
    u16* xTb = xT + (size_t)b * 4096 * 512;
    int t = threadIdx.x;
    int fl = *dt;
    const size_t xbase = (size_t)b * 512 * 4096;
    if (fl == 1) {
        const float* xb = (const float*)xv + xbase;
        int cr = t >> 4, n4 = (t & 15) * 4;
        #pragma unroll
        for (int i = 0; i < 4; i++) {
            int c = cr + i * 16;
            float4 v = *reinterpret_cast<const float4*>(xb + (size_t)(c0 + c) * 4096 + n0 + n4);
            tile[n4 + 0][c] = f2bf(v.x); tile[n4 + 1][c] = f2bf(v.y);
            tile[n4 + 2][c] = f2bf(v.z); tile[n4 + 3][c] = f2bf(v.w);
        }
    } else {
        int c4 = t >> 6, n = t & 63;
        for (int i = 0; i < 16; i++) {
            int c = c4 + i * 4;
            tile[n][c] = f2bf(loadElem(xv, xbase + (size_t)(c0 + c) * 4096 + n0 + n, fl));
        }
    }
    __syncthreads();
    int nr = t >> 3, c8 = (t & 7) * 8;
    #pragma unroll
    for (int i = 0; i < 2; i++) {
        int n = nr + i * 32;
        V16 v;
        #pragma unroll
        for (int j = 0; j < 8; j++) v.e[j] = tile[n][c8 + j];
        *reinterpret_cast<uint4*>(xTb + (size_t)(n0 + n) * 512 + c0 + c8) = v.v;
    }
}

// ---------------- fold mean through kW1/vW cols [0,512): per-(b,o) f32 bias ----------------
__global__ __launch_bounds__(64) void k_consts(const void* __restrict__ kW1, const void* __restrict__ vW,
                                               const int* __restrict__ dt, const float* __restrict__ xg,
                                               float* __restrict__ ck, float* __restrict__ cv) {
    int bo = blockIdx.x; int b = bo >> 8; int o = bo & 255;
    int l = threadIdx.x;
    int fl = *dt;
    const float* g = xg + b * 512;
    float sk = 0.f, sv = 0.f;
    for (int c = l; c < 512; c += 64) {
        float xv = g[c];
        sk += loadElem(kW1, (size_t)o * 1024 + c, fl) * xv;
        sv += loadElem(vW,  (size_t)o * 1024 + c, fl) * xv;
    }
    #pragma unroll
    for (int m = 32; m >= 1; m >>= 1) { sk += __shfl_xor(sk, m); sv += __shfl_xor(sv, m); }
    if (l == 0) { ck[bo] = sk; cv[bo] = sv; }
}

// ---------------- weights -> bf16 into ws ----------------
__global__ __launch_bounds__(256) void k_wconv(const void* __restrict__ qW1, const void* __restrict__ qW2,
                                               const void* __restrict__ kW1, const void* __restrict__ kW2,
                                               const void* __restrict__ vW, const void* __restrict__ oW,
                                               const int* __restrict__ dt, u16* __restrict__ dst) {
    int i = blockIdx.x * 256 + threadIdx.x;
    int fl = *dt;
    const void* s; size_t so;
    if (i < 131072)      { s = qW1; so = (size_t)i; }
    else if (i < 196608) { int j = i - 131072; s = qW2; so = (size_t)j; }
    else if (i < 327680) { int j = i - 196608; s = kW1; so = (size_t)(j >> 9) * 1024 + 512 + (j & 511); }
    else if (i < 393216) { int j = i - 327680; s = kW2; so = (size_t)j; }
    else if (i < 524288) { int j = i - 393216; s = vW;  so = (size_t)(j >> 9) * 1024 + 512 + (j & 511); }
    else                 { int j = i - 524288; s = oW;  so = (size_t)j; }
    dst[i] = f2bf(loadElem(s, so, fl));
}

// ---------------- affine params -> f32 into ws ----------------
__global__ __launch_bounds__(256) void k_pconv(const void* qg1, const void* qb1, const void* qg2, const void* qb2,
                                               const void* kg1, const void* kb1, const void* kg2, const void* kb2,
                                               const void* vg, const void* vb, const void* og, const void* ob,
                                               const int* __restrict__ dt, float* __restrict__ pg) {
    int j = blockIdx.x * 256 + threadIdx.x;
    if (j >= 3584) return;
    int fl = *dt;
    const void* s; int o;
    if (j < 256)       { s = qg1; o = j; }
    else if (j < 512)  { s = qb1; o = j - 256; }
    else if (j < 768)  { s = qg2; o = j - 512; }
    else if (j < 1024) { s = qb2; o = j - 768; }
    else if (j < 1280) { s = kg1; o = j - 1024; }
    else if (j < 1536) { s = kb1; o = j - 1280; }
    else if (j < 1792) { s = kg2; o = j - 1536; }
    else if (j < 2048) { s = kb2; o = j - 1792; }
    else if (j < 2304) { s = vg;  o = j - 2048; }
    else if (j < 2560) { s = vb;  o = j - 2304; }
    else if (j < 3072) { s = og;  o = j - 2560; }
    else               { s = ob;  o = j - 3072; }
    pg[j] = loadElem(s, (size_t)o, fl);
}

// ---------------- gemm_bt v2: async dbuf staging via global_load_lds (inverse-swizzled source) ----
template<bool AFF_ROW, typename OT>
__global__ __launch_bounds__(256) void k_gemm_bt(
    const u16* __restrict__ A, long aBS, int lda,
    const u16* __restrict__ Bm, long bBS, int ldb,
    OT* __restrict__ C, long cBS, int ldc,
    const float* __restrict__ gamma, const float* __restrict__ beta,
    const float* __restrict__ bias, int biasBS, int K) {
    __shared__ u16 As[2][128 * 64];
    __shared__ u16 Bs[2][128 * 64];
    int b = blockIdx.z;
    const u16* Ab = A + (size_t)b * aBS;
    const u16* Bb = Bm + (size_t)b * bBS;
    OT* Cb = C + (size_t)b * cBS;
    int m0 = blockIdx.x * 128, n0 = blockIdx.y * 128;
    int t = threadIdx.x;
    int lane = t & 63, wid = t >> 6;
    int wr = wid >> 1, wc = wid & 1;
    int li = lane & 15, lk = lane >> 4;

    f32x4 acc[4][4] = {};

    // stage one 16KB A-tile + 16KB B-tile (k-step k0) into buf: 4+4 gll per thread-slot
    auto stage = [&](int k0, int buf) {
        #pragma unroll
        for (int j = 0; j < 4; j++) {
            int c = wid * 4 + j;                       // chunk 0..15 (1KB each)
            u32 pl = (u32)c * 1024 + (u32)lane * 16;   // linear byte pos in tile
            u32 r = pl >> 7;                           // 128B per row
            u32 q = (pl & 127) ^ ((r & 7) << 4);       // inverse of read swizzle
            gll16(Ab + (size_t)(m0 + r) * lda + k0 + (q >> 1), &As[buf][0] + (c << 9));
            gll16(Bb + (size_t)(n0 + r) * ldb + k0 + (q >> 1), &Bs[buf][0] + (c << 9));
        }
    };

    const int nk = K >> 6;
    stage(0, 0);

    for (int kst = 0; kst < nk; kst++) {
        int cur = kst & 1;
        if (kst + 1 < nk) {
            stage((kst + 1) << 6, cur ^ 1);
            asm volatile("s_waitcnt vmcnt(8)" ::: "memory");   // tile kst landed; kst+1 in flight
        } else {
            asm volatile("s_waitcnt vmcnt(0)" ::: "memory");
        }
        __builtin_amdgcn_sched_barrier(0);
        __builtin_amdgcn_s_barrier();

        const char* AsB = (const char*)&As[cur][0];
        const char* BsB = (const char*)&Bs[cur][0];
        #pragma unroll
        for (int ks = 0; ks < 2; ks++) {
            bf16x8 af[4], bfr[4];
            #pragma unroll
            for (int mi = 0; mi < 4; mi++) {
                int r = wr * 64 + mi * 16 + li;
                u32 off = ((u32)(r * 128 + (ks * 32 + lk * 8) * 2)) ^ (((u32)(r & 7)) << 4);
                af[mi] = *reinterpret_cast<const bf16x8*>(AsB + off);
            }
            #pragma unroll
            for (int ni = 0; ni < 4; ni++) {
                int r = wc * 64 + ni * 16 + li;
                u32 off = ((u32)(r * 128 + (ks * 32 + lk * 8) * 2)) ^ (((u32)(r & 7)) << 4);
                bfr[ni] = *reinterpret_cast<const bf16x8*>(BsB + off);
            }
            #pragma unroll
            for (int mi = 0; mi < 4; mi++)
                #pragma unroll
                for (int ni = 0; ni < 4; ni++)
                    acc[mi][ni] = mfma16(af[mi], bfr[ni], acc[mi][ni]);
        }
        asm volatile("s_waitcnt lgkmcnt(0)" ::: "memory");
        __builtin_amdgcn_s_barrier();   // all waves done reading buf[cur]; next gll may overwrite
    }
    #pragma unroll
    for (int mi = 0; mi < 4; mi++) {
        #pragma unroll
        for (int ni = 0; ni < 4; ni++) {
            #pragma unroll
            for (int r = 0; r < 4; r++) {
                int m = m0 + wr * 64 + mi * 16 + lk * 4 + r;
                int n = n0 + wc * 64 + ni * 16 + li;
                int oc = AFF_ROW ? m : n;
                float v = acc[mi][ni][r];
                if (bias) v += bias[b * biasBS + oc];
                float y = v * gamma[oc] + beta[oc];
                y = fmaxf(y, 0.f);
                if constexpr (sizeof(OT) == 2) Cb[(size_t)m * ldc + n] = f2bf(y);
                else                           Cb[(size_t)m * ldc + n] = y;
            }
        }
    }
}

// ---------------- flash attention v4 (round-10 exact): swapped QK^T + async dbuf K/V ----------------
__global__ __launch_bounds__(256, 2) void k_attn(const u16* __restrict__ Q, const u16* __restrict__ Kt,
                                                 const u16* __restrict__ V, u16* __restrict__ Op,
                                                 float2* __restrict__ ML) {
    __shared__ u16 Ks[2][32 * 256];
    __shared__ u16 Vs[2][256 * 32];
    __shared__ u16 Ps[128 * 32];
    char* PsB = (char*)Ps;
    int wg = blockIdx.x;
    int bs = wg & 15, qt = wg >> 4;
    int b = bs >> 2, sp = bs & 3;
    int n0 = qt * 128;
    int k0 = sp * 1024;
    const size_t S = (size_t)4096 * 256;
    const u16* Qb = Q + (size_t)b * S + (size_t)n0 * 256;
    const u16* Kb = Kt + (size_t)b * S + (size_t)k0 * 256;
    const u16* Vb = V + (size_t)b * S + k0;      // channel-major [256][4096]
    int t = threadIdx.x;
    int lane = t & 63, wid = t >> 6;
    int li = lane & 15, lk = lane >> 4;
    int qw = wid * 32;

    // Q B-fragments (query = fq*16+li, d-chunk = kc*32+lk*8)
    bf16x8 qf[2][8];
    #pragma unroll
    for (int fq = 0; fq < 2; fq++)
        #pragma unroll
        for (int kc = 0; kc < 8; kc++)
            qf[fq][kc] = *reinterpret_cast<const bf16x8*>(Qb + (size_t)(qw + fq * 16 + li) * 256 + kc * 32 + lk * 8);

    f32x4 acc[2][16] = {};
    float M[2] = {-1e30f, -1e30f}, L[2] = {0.f, 0.f};
    const float SCL = 0.0625f * 1.44269504088896f;

    // async stage of one 16KB K-tile + 16KB V-tile: 4+4 gll calls per wave
    auto stage = [&](int kt, int buf) {
        const u16* Kp = Kb + (size_t)kt * 32 * 256;
        const u16* Vp = Vb + kt * 32;
        u16* Kd = &Ks[buf][0];
        u16* Vd = &Vs[buf][0];
        #pragma unroll
        for (int j = 0; j < 4; j++) {
            int c = wid * 4 + j;
            u32 pl = (u32)c * 1024 + (u32)lane * 16;      // linear byte pos in tile
            u32 krow = pl >> 9;
            u32 kq = (pl & 511) ^ ((krow & 7) << 4);       // inverse of read swizzle
            gll16(Kp + krow * 256 + (kq >> 1), Kd + (c << 9));
            u32 vcc = pl >> 6;
            u32 vq = (pl & 63) ^ (((vcc >> 1) & 3) << 4);  // inverse of read swizzle
            gll16(Vp + (size_t)vcc * 4096 + (vq >> 1), Vd + (c << 9));
        }
    };

    stage(0, 0);

    for (int kt = 0; kt < 32; kt++) {
        int cur = kt & 1;
        if (kt + 1 < 32) {
            stage(kt + 1, cur ^ 1);
            asm volatile("s_waitcnt vmcnt(8)" ::: "memory");   // tile kt landed; kt+1 in flight
        } else {
            asm volatile("s_waitcnt vmcnt(0)" ::: "memory");
        }
        __builtin_amdgcn_sched_barrier(0);
        __builtin_amdgcn_s_barrier();

        const char* KsB = (const char*)&Ks[cur][0];
        const char* VsB = (const char*)&Vs[cur][0];

        // S^T = K · Q : sf[mk][fq], key = mk*16+lk*4+r, query = fq*16+li
        __builtin_amdgcn_s_setprio(1);
        f32x4 sf[2][2] = {};
        #pragma unroll
        for (int mk = 0; mk < 2; mk++) {
            #pragma unroll
            for (int kc = 0; kc < 8; kc++) {
                int row = mk * 16 + li;
                u32 off = (u32)(row * 512) + (((u32)(kc * 64 + lk * 16)) ^ (((u32)(row & 7)) << 4));
                bf16x8 kb = *reinterpret_cast<const bf16x8*>(KsB + off);
                sf[mk][0] = mfma16(kb, qf[0][kc], sf[mk][0]);
                sf[mk][1] = mfma16(kb, qf[1][kc], sf[mk][1]);
            }
        }
        __builtin_amdgcn_s_setprio(0);

        // online softmax: in-register (2 shuffles per fq for max, 2 for sum)
        float pm[2];
        #pragma unroll
        for (int fq = 0; fq < 2; fq++) {
            float mx = fmaxf(fmaxf(fmaxf(sf[0][fq][0], sf[0][fq][1]), fmaxf(sf[0][fq][2], sf[0][fq][3])),
                             fmaxf(fmaxf(sf[1][fq][0], sf[1][fq][1]), fmaxf(sf[1][fq][2], sf[1][fq][3])));
            mx = fmaxf(mx, __shfl_xor(mx, 16));
            mx = fmaxf(mx, __shfl_xor(mx, 32));
            pm[fq] = mx * SCL;
        }
        bool ok = (pm[0] <= M[0] + 8.f) && (pm[1] <= M[1] + 8.f);
        if (!__all(ok ? 1 : 0)) {
            #pragma unroll
            for (int fq = 0; fq < 2; fq++) {
                float nM = fmaxf(M[fq], pm[fq]);
                float rs = exp2f(M[fq] - nM);
                L[fq] *= rs; M[fq] = nM;
                #pragma unroll
                for (int ct = 0; ct < 16; ct++) {
                    acc[fq][ct][0] *= rs; acc[fq][ct][1] *= rs;
                    acc[fq][ct][2] *= rs; acc[fq][ct][3] *= rs;
                }
            }
        }
        #pragma unroll
        for (int fq = 0; fq < 2; fq++) {
            int row = qw + fq * 16 + li;
            float rowsum = 0.f;
            #pragma unroll
            for (int mk = 0; mk < 2; mk++) {
                float p0 = exp2f(sf[mk][fq][0] * SCL - M[fq]);
                float p1 = exp2f(sf[mk][fq][1] * SCL - M[fq]);
                float p2 = exp2f(sf[mk][fq][2] * SCL - M[fq]);
                float p3 = exp2f(sf[mk][fq][3] * SCL - M[fq]);
                rowsum += (p0 + p1) + (p2 + p3);
                uint2 pw; pw.x = pack2(p0, p1); pw.y = pack2(p2, p3);
                u32 off = ((u32)(row * 64 + mk * 32 + lk * 8)) ^ (((u32)(row & 7)) << 4);
                *reinterpret_cast<uint2*>(PsB + off) = pw;
            }
            rowsum += __shfl_xor(rowsum, 16);
            rowsum += __shfl_xor(rowsum, 32);
            L[fq] += rowsum;
        }

        // O^T += V^T · P^T  (Ps rows wave-private)
        __builtin_amdgcn_s_setprio(1);
        {
            bf16x8 pb[2];
            #pragma unroll
            for (int fq = 0; fq < 2; fq++) {
                int row = qw + fq * 16 + li;
                u32 off = ((u32)(row * 64 + lk * 16)) ^ (((u32)(row & 7)) << 4);
                pb[fq] = *reinterpret_cast<const bf16x8*>(PsB + off);
            }
            #pragma unroll
            for (int ct = 0; ct < 16; ct++) {
                int vr = ct * 16 + li;
                u32 voff = (u32)(vr * 64) + (((u32)(lk * 16)) ^ (((u32)((vr >> 1) & 3)) << 4));
                bf16x8 va = *reinterpret_cast<const bf16x8*>(VsB + voff);
                acc[0][ct] = mfma16(va, pb[0], acc[0][ct]);
                acc[1][ct] = mfma16(va, pb[1], acc[1][ct]);
            }
        }
        __builtin_amdgcn_s_setprio(0);
        asm volatile("s_waitcnt lgkmcnt(0)" ::: "memory");
        __builtin_amdgcn_s_barrier();   // all waves done reading buf[cur]; next gll may overwrite it
    }

    // epilogue: unnormalized partials (query per lane-col, channels packed 4-wide)
    size_t obase = (size_t)(sp * 4 + b) * 4096 + n0;
    #pragma unroll
    for (int fq = 0; fq < 2; fq++) {
        int q = qw + fq * 16 + li;
        #pragma unroll
        for (int ct = 0; ct < 16; ct++) {
            uint2 ow;
            ow.x = pack2(acc[fq][ct][0], acc[fq][ct][1]);
            ow.y = pack2(acc[fq][ct][2], acc[fq][ct][3]);
            *reinterpret_cast<uint2*>(&Op[(obase + q) * 256 + ct * 16 + lk * 4]) = ow;
        }
    }
    if (lk == 0) {
        #pragma unroll
        for (int fq = 0; fq < 2; fq++) {
            float2 v; v.x = M[fq]; v.y = L[fq];
            ML[obase + qw + fq * 16 + li] = v;
        }
    }
}

// ---------------- merge split-KV partials -> ctx bf16 [b][4096][256] ----------------
__global__ __launch_bounds__(256) void k_merge(const u16* __restrict__ Op, const float2* __restrict__ ML,
                                               u16* __restrict__ ctx) {
    int wg = blockIdx.x;               // 16384 = 4b x 4096q
    int t = threadIdx.x;               // ch
    int b = wg >> 12, q = wg & 4095;
    float2 ml[4];
    float Mx = -1e30f;
    #pragma unroll
    for (int s = 0; s < 4; s++) { ml[s] = ML[((size_t)(s * 4 + b) << 12) + q]; Mx = fmaxf(Mx, ml[s].x); }
    float Lt = 0.f, w[4];
    #pragma unroll
    for (int s = 0; s < 4; s++) { w[s] = exp2f(ml[s].x - Mx); Lt += ml[s].y * w[s]; }
    float inv = 1.f / Lt;
    float o = 0.f;
    #pragma unroll
    for (int s = 0; s < 4; s++)
        o += w[s] * bf2f(Op[((((size_t)(s * 4 + b) << 12) + q)) * 256 + t]);
    ctx[(((size_t)b << 12) + q) * 256 + t] = f2bf(o * inv);
}

extern "C" void kernel_launch(void* const* d_in, const int* in_sizes, int n_in,
                              void* d_out, int out_size, void* d_ws, size_t ws_size,
                              hipStream_t stream) {
    const void* x   = d_in[0];
    const void* qW1 = d_in[1];  const void* qg1 = d_in[2];  const void* qb1 = d_in[3];
    const void* qW2 = d_in[4];  const void* qg2 = d_in[5];  const void* qb2 = d_in[6];
    const void* kW1 = d_in[7];  const void* kg1 = d_in[8];  const void* kb1 = d_in[9];
    const void* kW2 = d_in[10]; const void* kg2 = d_in[11]; const void* kb2 = d_in[12];
    const void* vW  = d_in[13]; const void* vg  = d_in[14]; const void* vb  = d_in[15];
    const void* oW  = d_in[16]; const void* og  = d_in[17]; const void* ob  = d_in[18];

    char* ws = (char*)d_ws;
    int*   dflag = (int*)ws;
    float* xg = (float*)(ws + 4096);
    float* ck = (float*)(ws + 16384);
    float* cv = (float*)(ws + 20480);
    float* pg = (float*)(ws + 24576);
    u16* wb = (u16*)(ws + 40960);              // 655360 bf16 weights, ends at byte 1,351,680
    u16* qW1b = wb;
    u16* qW2b = wb + 131072;
    u16* kW1b = wb + 196608;
    u16* kW2b = wb + 327680;
    u16* vWb  = wb + 393216;
    u16* oWb  = wb + 524288;
    const size_t S = (size_t)4096 * 256;
    const size_t SLOT = 4 * S;
    u16* s0 = (u16*)(ws + 0x180000);           // slots start at 1.5 MiB (clear of wb)
    u16* s1 = s0 + SLOT;
    u16* s2 = s1 + SLOT;
    u16* s3 = s2 + SLOT;
    float2* mlBuf = (float2*)s3;               // ML lives in s3 (free during attn)
    u16* xT = (u16*)d_out;                     // bf16 scratch in d_out; dead before attn
    u16* opart = (u16*)d_out;                  // attn partials [16][4096][256] bf16 = full d_out
    u16* ctxBuf = s1;                          // ctx into s1 (Q dead after attn)

    k_detect<<<1, 256, 0, stream>>>((const u32*)x, dflag);
    k_mean<<<2048, 256, 0, stream>>>(x, dflag, xg);
    k_xpose<<<dim3(64, 8, 4), 256, 0, stream>>>(x, dflag, xT);
    k_consts<<<1024, 64, 0, stream>>>(kW1, vW, dflag, xg, ck, cv);
    k_wconv<<<2560, 256, 0, stream>>>(qW1, qW2, kW1, kW2, vW, oW, dflag, wb);
    k_pconv<<<14, 256, 0, stream>>>(qg1, qb1, qg2, qb2, kg1, kb1, kg2, kb2,
                                    vg, vb, og, ob, dflag, pg);

    const long XS = (long)4096 * 512;
    // q1 -> s0
    k_gemm_bt<false, u16><<<dim3(32, 2, 4), 256, 0, stream>>>(xT, XS, 512, qW1b, 0, 512,
        s0, (long)S, 256, pg + 0, pg + 256, nullptr, 0, 512);
    // q2 -> s1
    k_gemm_bt<false, u16><<<dim3(32, 2, 4), 256, 0, stream>>>(s0, (long)S, 256, qW2b, 0, 256,
        s1, (long)S, 256, pg + 512, pg + 768, nullptr, 0, 256);
    // k1 (folded-mean bias ck) -> s0
    k_gemm_bt<false, u16><<<dim3(32, 2, 4), 256, 0, stream>>>(xT, XS, 512, kW1b, 0, 512,
        s0, (long)S, 256, pg + 1024, pg + 1280, ck, 256, 512);
    // k2 -> s2
    k_gemm_bt<false, u16><<<dim3(32, 2, 4), 256, 0, stream>>>(s0, (long)S, 256, kW2b, 0, 256,
        s2, (long)S, 256, pg + 1536, pg + 1792, nullptr, 0, 256);
    // v (channel-major, bias cv) -> s0
    k_gemm_bt<true, u16><<<dim3(2, 32, 4), 256, 0, stream>>>(vWb, 0, 512, xT, XS, 512,
        s0, (long)S, 4096, pg + 2048, pg + 2304, cv, 256, 512);
    // attention (split-KV x4): Q(s1), K(s2), V(s0) -> partials in d_out, ML in s3
    k_attn<<<512, 256, 0, stream>>>(s1, s2, s0, opart, mlBuf);
    // merge -> ctx (s1; Q dead)
    k_merge<<<16384, 256, 0, stream>>>(opart, mlBuf, ctxBuf);
    // out projection -> d_out as f32 [B][512][4096]
    k_gemm_bt<true, float><<<dim3(4, 32, 4), 256, 0, stream>>>(oWb, 0, 256, ctxBuf, (long)S, 256,
        (float*)d_out, (long)512 * 4096, 4096, pg + 2560, pg + 3072, nullptr, 0, 256);
}

// Round 13
// 226.230 us; speedup vs baseline: 1.9809x; 1.1597x over previous
//
#include <hip/hip_runtime.h>
#include <stdint.h>

typedef __bf16 bf16x8 __attribute__((ext_vector_type(8)));
typedef float f32x4 __attribute__((ext_vector_type(4)));
typedef unsigned short u16;
typedef uint32_t u32;

union V16 { uint4 v; u16 e[8]; };

__device__ __forceinline__ float bf2f(u16 h) {
    u32 u = ((u32)h) << 16; float f; __builtin_memcpy(&f, &u, 4); return f;
}
__device__ __forceinline__ u16 f2bf(float f) {
    u32 u; __builtin_memcpy(&u, &f, 4);
    u32 r = (u + 0x7FFFu + ((u >> 16) & 1u)) >> 16; return (u16)r;
}
__device__ __forceinline__ u32 pack2(float a, float b) {
    return (u32)f2bf(a) | ((u32)f2bf(b) << 16);
}
__device__ __forceinline__ f32x4 mfma16(bf16x8 a, bf16x8 b, f32x4 c) {
    return __builtin_amdgcn_mfma_f32_16x16x32_bf16(a, b, c, 0, 0, 0);
}
// async 16B global -> LDS (wave-uniform LDS base; HW adds lane*16)
__device__ __forceinline__ void gll16(const u16* g, u16* l) {
    __builtin_amdgcn_global_load_lds(
        (const __attribute__((address_space(1))) unsigned int*)g,
        (__attribute__((address_space(3))) unsigned int*)l, 16, 0, 0);
}
// flag: 0=bf16, 1=f32, 2=f64
__device__ __forceinline__ float loadElem(const void* p, size_t i, int fl) {
    if (fl == 1) return ((const float*)p)[i];
    if (fl == 2) return (float)((const double*)p)[i];
    return bf2f(((const u16*)p)[i]);
}

// ---------------- dtype detect on x ----------------
__global__ __launch_bounds__(256) void k_detect(const u32* __restrict__ xw, int* __restrict__ flag) {
    int t = threadIdx.x;
    int cA = 0, cB = 0;
    #pragma unroll
    for (int i = 0; i < 16; i++) {
        u32 w = xw[i * 256 + t];
        cA += (((w >> 23) & 0xFFu) >= 0xC0u) ? 1 : 0;
        cB += (((w >> 7)  & 0xFFu) >= 0xC0u) ? 1 : 0;
    }
    #pragma unroll
    for (int m = 32; m >= 1; m >>= 1) { cA += __shfl_xor(cA, m); cB += __shfl_xor(cB, m); }
    __shared__ int sA[4], sB[4];
    if ((t & 63) == 0) { sA[t >> 6] = cA; sB[t >> 6] = cB; }
    __syncthreads();
    if (t == 0) {
        int a = sA[0] + sA[1] + sA[2] + sA[3];
        int b = sB[0] + sB[1] + sB[2] + sB[3];
        *flag = (a > 64) ? 2 : ((b > 64) ? 1 : 0);
    }
}

// ---------------- mean over HW: xg[b*512+c] ----------------
__global__ __launch_bounds__(256) void k_mean(const void* __restrict__ xv, const int* __restrict__ dt,
                                              float* __restrict__ xg) {
    int bc = blockIdx.x;
    int t = threadIdx.x;
    int fl = *dt;
    const size_t base = (size_t)bc * 4096;
    float s = 0.f;
    if (fl == 1) {
        const float* p = (const float*)xv + base;
        #pragma unroll
        for (int i = 0; i < 4; i++) {
            float4 v = *reinterpret_cast<const float4*>(p + (size_t)(i * 256 + t) * 4);
            s += v.x + v.y + v.z + v.w;
        }
    } else {
        for (int i = 0; i < 16; i++) s += loadElem(xv, base + i * 256 + t, fl);
    }
    #pragma unroll
    for (int m = 32; m >= 1; m >>= 1) s += __shfl_xor(s, m);
    __shared__ float wsum[4];
    if ((t & 63) == 0) wsum[t >> 6] = s;
    __syncthreads();
    if (t == 0) xg[bc] = (wsum[0] + wsum[1] + wsum[2] + wsum[3]) * (1.f / 4096.f);
}

// ---------------- transpose(+cast) x [B][512][4096] -> xT bf16 [B][4096][512] ----------------
__global__ __launch_bounds__(256) void k_xpose(const void* __restrict__ xv, const int* __restrict__ dt,
                                               u16* __restrict__ xT) {
    __shared__ u16 tile[64][72];
    int b = blockIdx.z;
    int n0 = blockIdx.x * 64, c0 = blockIdx.y * 64;
    u16* xTb = xT + (size_t)b * 4096 * 512;
    int t = threadIdx.x;
    int fl = *dt;
    const size_t xbase = (size_t)b * 512 * 4096;
    if (fl == 1) {
        const float* xb = (const float*)xv + xbase;
        int cr = t >> 4, n4 = (t & 15) * 4;
        #pragma unroll
        for (int i = 0; i < 4; i++) {
            int c = cr + i * 16;
            float4 v = *reinterpret_cast<const float4*>(xb + (size_t)(c0 + c) * 4096 + n0 + n4);
            tile[n4 + 0][c] = f2bf(v.x); tile[n4 + 1][c] = f2bf(v.y);
            tile[n4 + 2][c] = f2bf(v.z); tile[n4 + 3][c] = f2bf(v.w);
        }
    } else {
        int c4 = t >> 6, n = t & 63;
        for (int i = 0; i < 16; i++) {
            int c = c4 + i * 4;
            tile[n][c] = f2bf(loadElem(xv, xbase + (size_t)(c0 + c) * 4096 + n0 + n, fl));
        }
    }
    __syncthreads();
    int nr = t >> 3, c8 = (t & 7) * 8;
    #pragma unroll
    for (int i = 0; i < 2; i++) {
        int n = nr + i * 32;
        V16 v;
        #pragma unroll
        for (int j = 0; j < 8; j++) v.e[j] = tile[n][c8 + j];
        *reinterpret_cast<uint4*>(xTb + (size_t)(n0 + n) * 512 + c0 + c8) = v.v;
    }
}

// ---------------- fold mean through kW1/vW cols [0,512): per-(b,o) f32 bias ----------------
__global__ __launch_bounds__(64) void k_consts(const void* __restrict__ kW1, const void* __restrict__ vW,
                                               const int* __restrict__ dt, const float* __restrict__ xg,
                                               float* __restrict__ ck, float* __restrict__ cv) {
    int bo = blockIdx.x; int b = bo >> 8; int o = bo & 255;
    int l = threadIdx.x;
    int fl = *dt;
    const float* g = xg + b * 512;
    float sk = 0.f, sv = 0.f;
    for (int c = l; c < 512; c += 64) {
        float xv = g[c];
        sk += loadElem(kW1, (size_t)o * 1024 + c, fl) * xv;
        sv += loadElem(vW,  (size_t)o * 1024 + c, fl) * xv;
    }
    #pragma unroll
    for (int m = 32; m >= 1; m >>= 1) { sk += __shfl_xor(sk, m); sv += __shfl_xor(sv, m); }
    if (l == 0) { ck[bo] = sk; cv[bo] = sv; }
}

// ---------------- weights -> bf16 into ws ----------------
__global__ __launch_bounds__(256) void k_wconv(const void* __restrict__ qW1, const void* __restrict__ qW2,
                                               const void* __restrict__ kW1, const void* __restrict__ kW2,
                                               const void* __restrict__ vW, const void* __restrict__ oW,
                                               const int* __restrict__ dt, u16* __restrict__ dst) {
    int i = blockIdx.x * 256 + threadIdx.x;
    int fl = *dt;
    const void* s; size_t so;
    if (i < 131072)      { s = qW1; so = (size_t)i; }
    else if (i < 196608) { int j = i - 131072; s = qW2; so = (size_t)j; }
    else if (i < 327680) { int j = i - 196608; s = kW1; so = (size_t)(j >> 9) * 1024 + 512 + (j & 511); }
    else if (i < 393216) { int j = i - 327680; s = kW2; so = (size_t)j; }
    else if (i < 524288) { int j = i - 393216; s = vW;  so = (size_t)(j >> 9) * 1024 + 512 + (j & 511); }
    else                 { int j = i - 524288; s = oW;  so = (size_t)j; }
    dst[i] = f2bf(loadElem(s, so, fl));
}

// ---------------- affine params -> f32 into ws ----------------
__global__ __launch_bounds__(256) void k_pconv(const void* qg1, const void* qb1, const void* qg2, const void* qb2,
                                               const void* kg1, const void* kb1, const void* kg2, const void* kb2,
                                               const void* vg, const void* vb, const void* og, const void* ob,
                                               const int* __restrict__ dt, float* __restrict__ pg) {
    int j = blockIdx.x * 256 + threadIdx.x;
    if (j >= 3584) return;
    int fl = *dt;
    const void* s; int o;
    if (j < 256)       { s = qg1; o = j; }
    else if (j < 512)  { s = qb1; o = j - 256; }
    else if (j < 768)  { s = qg2; o = j - 512; }
    else if (j < 1024) { s = qb2; o = j - 768; }
    else if (j < 1280) { s = kg1; o = j - 1024; }
    else if (j < 1536) { s = kb1; o = j - 1280; }
    else if (j < 1792) { s = kg2; o = j - 1536; }
    else if (j < 2048) { s = kb2; o = j - 1792; }
    else if (j < 2304) { s = vg;  o = j - 2048; }
    else if (j < 2560) { s = vb;  o = j - 2304; }
    else if (j < 3072) { s = og;  o = j - 2560; }
    else               { s = ob;  o = j - 3072; }
    pg[j] = loadElem(s, (size_t)o, fl);
}

// ---------------- gemm_bt v2: async dbuf staging via global_load_lds ----------------
template<bool AFF_ROW, typename OT>
__global__ __launch_bounds__(256) void k_gemm_bt(
    const u16* __restrict__ A, long aBS, int lda,
    const u16* __restrict__ Bm, long bBS, int ldb,
    OT* __restrict__ C, long cBS, int ldc,
    const float* __restrict__ gamma, const float* __restrict__ beta,
    const float* __restrict__ bias, int biasBS, int K) {
    __shared__ u16 As[2][128 * 64];
    __shared__ u16 Bs[2][128 * 64];
    int b = blockIdx.z;
    const u16* Ab = A + (size_t)b * aBS;
    const u16* Bb = Bm + (size_t)b * bBS;
    OT* Cb = C + (size_t)b * cBS;
    int m0 = blockIdx.x * 128, n0 = blockIdx.y * 128;
    int t = threadIdx.x;
    int lane = t & 63, wid = t >> 6;
    int wr = wid >> 1, wc = wid & 1;
    int li = lane & 15, lk = lane >> 4;

    f32x4 acc[4][4] = {};

    auto stage = [&](int k0, int buf) {
        #pragma unroll
        for (int j = 0; j < 4; j++) {
            int c = wid * 4 + j;
            u32 pl = (u32)c * 1024 + (u32)lane * 16;
            u32 r = pl >> 7;
            u32 q = (pl & 127) ^ ((r & 7) << 4);
            gll16(Ab + (size_t)(m0 + r) * lda + k0 + (q >> 1), &As[buf][0] + (c << 9));
            gll16(Bb + (size_t)(n0 + r) * ldb + k0 + (q >> 1), &Bs[buf][0] + (c << 9));
        }
    };

    const int nk = K >> 6;
    stage(0, 0);

    for (int kst = 0; kst < nk; kst++) {
        int cur = kst & 1;
        if (kst + 1 < nk) {
            stage((kst + 1) << 6, cur ^ 1);
            asm volatile("s_waitcnt vmcnt(8)" ::: "memory");
        } else {
            asm volatile("s_waitcnt vmcnt(0)" ::: "memory");
        }
        __builtin_amdgcn_sched_barrier(0);
        __builtin_amdgcn_s_barrier();

        const char* AsB = (const char*)&As[cur][0];
        const char* BsB = (const char*)&Bs[cur][0];
        #pragma unroll
        for (int ks = 0; ks < 2; ks++) {
            bf16x8 af[4], bfr[4];
            #pragma unroll
            for (int mi = 0; mi < 4; mi++) {
                int r = wr * 64 + mi * 16 + li;
                u32 off = ((u32)(r * 128 + (ks * 32 + lk * 8) * 2)) ^ (((u32)(r & 7)) << 4);
                af[mi] = *reinterpret_cast<const bf16x8*>(AsB + off);
            }
            #pragma unroll
            for (int ni = 0; ni < 4; ni++) {
                int r = wc * 64 + ni * 16 + li;
                u32 off = ((u32)(r * 128 + (ks * 32 + lk * 8) * 2)) ^ (((u32)(r & 7)) << 4);
                bfr[ni] = *reinterpret_cast<const bf16x8*>(BsB + off);
            }
            #pragma unroll
            for (int mi = 0; mi < 4; mi++)
                #pragma unroll
                for (int ni = 0; ni < 4; ni++)
                    acc[mi][ni] = mfma16(af[mi], bfr[ni], acc[mi][ni]);
        }
        asm volatile("s_waitcnt lgkmcnt(0)" ::: "memory");
        __builtin_amdgcn_s_barrier();
    }
    #pragma unroll
    for (int mi = 0; mi < 4; mi++) {
        #pragma unroll
        for (int ni = 0; ni < 4; ni++) {
            #pragma unroll
            for (int r = 0; r < 4; r++) {
                int m = m0 + wr * 64 + mi * 16 + lk * 4 + r;
                int n = n0 + wc * 64 + ni * 16 + li;
                int oc = AFF_ROW ? m : n;
                float v = acc[mi][ni][r];
                if (bias) v += bias[b * biasBS + oc];
                float y = v * gamma[oc] + beta[oc];
                y = fmaxf(y, 0.f);
                if constexpr (sizeof(OT) == 2) Cb[(size_t)m * ldc + n] = f2bf(y);
                else                           Cb[(size_t)m * ldc + n] = y;
            }
        }
    }
}

// ---------------- fused pair gemm: blockIdx.z = op*4 + b (2 ops sharing one launch) ----------------
__global__ __launch_bounds__(256) void k_gemm_pair(
    const u16* __restrict__ A0, const u16* __restrict__ A1, long aBS, int lda,
    const u16* __restrict__ B0, const u16* __restrict__ B1, int ldb,
    u16* __restrict__ C0, u16* __restrict__ C1, long cBS, int ldc,
    const float* __restrict__ g0, const float* __restrict__ be0, const float* __restrict__ bias0,
    const float* __restrict__ g1, const float* __restrict__ be1, const float* __restrict__ bias1,
    int biasBS, int K) {
    __shared__ u16 As[2][128 * 64];
    __shared__ u16 Bs[2][128 * 64];
    int z = blockIdx.z;
    int op = z >> 2, b = z & 3;
    const u16* Ab = (op ? A1 : A0) + (size_t)b * aBS;
    const u16* Bb = op ? B1 : B0;
    u16* Cb = (op ? C1 : C0) + (size_t)b * cBS;
    const float* gamma = op ? g1 : g0;
    const float* beta  = op ? be1 : be0;
    const float* bias  = op ? bias1 : bias0;
    int m0 = blockIdx.x * 128, n0 = blockIdx.y * 128;
    int t = threadIdx.x;
    int lane = t & 63, wid = t >> 6;
    int wr = wid >> 1, wc = wid & 1;
    int li = lane & 15, lk = lane >> 4;

    f32x4 acc[4][4] = {};

    auto stage = [&](int k0, int buf) {
        #pragma unroll
        for (int j = 0; j < 4; j++) {
            int c = wid * 4 + j;
            u32 pl = (u32)c * 1024 + (u32)lane * 16;
            u32 r = pl >> 7;
            u32 q = (pl & 127) ^ ((r & 7) << 4);
            gll16(Ab + (size_t)(m0 + r) * lda + k0 + (q >> 1), &As[buf][0] + (c << 9));
            gll16(Bb + (size_t)(n0 + r) * ldb + k0 + (q >> 1), &Bs[buf][0] + (c << 9));
        }
    };

    const int nk = K >> 6;
    stage(0, 0);

    for (int kst = 0; kst < nk; kst++) {
        int cur = kst & 1;
        if (kst + 1 < nk) {
            stage((kst + 1) << 6, cur ^ 1);
            asm volatile("s_waitcnt vmcnt(8)" ::: "memory");
        } else {
            asm volatile("s_waitcnt vmcnt(0)" ::: "memory");
        }
        __builtin_amdgcn_sched_barrier(0);
        __builtin_amdgcn_s_barrier();

        const char* AsB = (const char*)&As[cur][0];
        const char* BsB = (const char*)&Bs[cur][0];
        #pragma unroll
        for (int ks = 0; ks < 2; ks++) {
            bf16x8 af[4], bfr[4];
            #pragma unroll
            for (int mi = 0; mi < 4; mi++) {
                int r = wr * 64 + mi * 16 + li;
                u32 off = ((u32)(r * 128 + (ks * 32 + lk * 8) * 2)) ^ (((u32)(r & 7)) << 4);
                af[mi] = *reinterpret_cast<const bf16x8*>(AsB + off);
            }
            #pragma unroll
            for (int ni = 0; ni < 4; ni++) {
                int r = wc * 64 + ni * 16 + li;
                u32 off = ((u32)(r * 128 + (ks * 32 + lk * 8) * 2)) ^ (((u32)(r & 7)) << 4);
                bfr[ni] = *reinterpret_cast<const bf16x8*>(BsB + off);
            }
            #pragma unroll
            for (int mi = 0; mi < 4; mi++)
                #pragma unroll
                for (int ni = 0; ni < 4; ni++)
                    acc[mi][ni] = mfma16(af[mi], bfr[ni], acc[mi][ni]);
        }
        asm volatile("s_waitcnt lgkmcnt(0)" ::: "memory");
        __builtin_amdgcn_s_barrier();
    }
    #pragma unroll
    for (int mi = 0; mi < 4; mi++) {
        #pragma unroll
        for (int ni = 0; ni < 4; ni++) {
            #pragma unroll
            for (int r = 0; r < 4; r++) {
                int m = m0 + wr * 64 + mi * 16 + lk * 4 + r;
                int n = n0 + wc * 64 + ni * 16 + li;
                float v = acc[mi][ni][r];
                if (bias) v += bias[b * biasBS + n];
                float y = v * gamma[n] + beta[n];
                y = fmaxf(y, 0.f);
                Cb[(size_t)m * ldc + n] = f2bf(y);
            }
        }
    }
}

// ---------------- flash attention v6: swapped QK^T + async dbuf + lane-local softmax ----------------
__global__ __launch_bounds__(256, 2) void k_attn(const u16* __restrict__ Q, const u16* __restrict__ Kt,
                                                 const u16* __restrict__ V, u16* __restrict__ Op,
                                                 float2* __restrict__ ML) {
    __shared__ u16 Ks[2][32 * 256];
    __shared__ u16 Vs[2][256 * 32];
    __shared__ u16 Ps[128 * 32];
    char* PsB = (char*)Ps;
    int wg = blockIdx.x;
    int bs = wg & 15, qt = wg >> 4;
    int b = bs >> 2, sp = bs & 3;
    int n0 = qt * 128;
    int k0 = sp * 1024;
    const size_t S = (size_t)4096 * 256;
    const u16* Qb = Q + (size_t)b * S + (size_t)n0 * 256;
    const u16* Kb = Kt + (size_t)b * S + (size_t)k0 * 256;
    const u16* Vb = V + (size_t)b * S + k0;      // channel-major [256][4096]
    int t = threadIdx.x;
    int lane = t & 63, wid = t >> 6;
    int li = lane & 15, lk = lane >> 4;
    int qw = wid * 32;

    bf16x8 qf[2][8];
    #pragma unroll
    for (int fq = 0; fq < 2; fq++)
        #pragma unroll
        for (int kc = 0; kc < 8; kc++)
            qf[fq][kc] = *reinterpret_cast<const bf16x8*>(Qb + (size_t)(qw + fq * 16 + li) * 256 + kc * 32 + lk * 8);

    f32x4 acc[2][16] = {};
    float M[2] = {-1e30f, -1e30f};
    float L[2] = {0.f, 0.f};          // per-lane partial (own 8 keys); butterfly at epilogue
    const float SCL = 0.0625f * 1.44269504088896f;

    auto stage = [&](int kt, int buf) {
        const u16* Kp = Kb + (size_t)kt * 32 * 256;
        const u16* Vp = Vb + kt * 32;
        u16* Kd = &Ks[buf][0];
        u16* Vd = &Vs[buf][0];
        #pragma unroll
        for (int j = 0; j < 4; j++) {
            int c = wid * 4 + j;
            u32 pl = (u32)c * 1024 + (u32)lane * 16;
            u32 krow = pl >> 9;
            u32 kq = (pl & 511) ^ ((krow & 7) << 4);
            gll16(Kp + krow * 256 + (kq >> 1), Kd + (c << 9));
            u32 vcc = pl >> 6;
            u32 vq = (pl & 63) ^ (((vcc >> 1) & 3) << 4);
            gll16(Vp + (size_t)vcc * 4096 + (vq >> 1), Vd + (c << 9));
        }
    };

    stage(0, 0);

    for (int kt = 0; kt < 32; kt++) {
        int cur = kt & 1;
        if (kt + 1 < 32) {
            stage(kt + 1, cur ^ 1);
            asm volatile("s_waitcnt vmcnt(8)" ::: "memory");
        } else {
            asm volatile("s_waitcnt vmcnt(0)" ::: "memory");
        }
        __builtin_amdgcn_sched_barrier(0);
        __builtin_amdgcn_s_barrier();

        const char* KsB = (const char*)&Ks[cur][0];
        const char* VsB = (const char*)&Vs[cur][0];

        // S^T = K · Q
        __builtin_amdgcn_s_setprio(1);
        f32x4 sf[2][2] = {};
        #pragma unroll
        for (int mk = 0; mk < 2; mk++) {
            #pragma unroll
            for (int kc = 0; kc < 8; kc++) {
                int row = mk * 16 + li;
                u32 off = (u32)(row * 512) + (((u32)(kc * 64 + lk * 16)) ^ (((u32)(row & 7)) << 4));
                bf16x8 kb = *reinterpret_cast<const bf16x8*>(KsB + off);
                sf[mk][0] = mfma16(kb, qf[0][kc], sf[mk][0]);
                sf[mk][1] = mfma16(kb, qf[1][kc], sf[mk][1]);
            }
        }
        __builtin_amdgcn_s_setprio(0);

        // lane-local max guard: cross-lane ops only in the rare rescale branch
        float lm[2];
        #pragma unroll
        for (int fq = 0; fq < 2; fq++) {
            lm[fq] = fmaxf(fmaxf(fmaxf(sf[0][fq][0], sf[0][fq][1]), fmaxf(sf[0][fq][2], sf[0][fq][3])),
                           fmaxf(fmaxf(sf[1][fq][0], sf[1][fq][1]), fmaxf(sf[1][fq][2], sf[1][fq][3]))) * SCL;
        }
        bool ok = (lm[0] <= M[0] + 24.f) && (lm[1] <= M[1] + 24.f);
        if (!__all(ok ? 1 : 0)) {
            #pragma unroll
            for (int fq = 0; fq < 2; fq++) {
                float mx = lm[fq];
                mx = fmaxf(mx, __shfl_xor(mx, 16));
                mx = fmaxf(mx, __shfl_xor(mx, 32));
                float nM = fmaxf(M[fq], mx);
                float rs = exp2f(M[fq] - nM);
                L[fq] *= rs; M[fq] = nM;
                #pragma unroll
                for (int ct = 0; ct < 16; ct++) {
                    acc[fq][ct][0] *= rs; acc[fq][ct][1] *= rs;
                    acc[fq][ct][2] *= rs; acc[fq][ct][3] *= rs;
                }
            }
        }
        #pragma unroll
        for (int fq = 0; fq < 2; fq++) {
            int row = qw + fq * 16 + li;
            float lloc = 0.f;
            #pragma unroll
            for (int mk = 0; mk < 2; mk++) {
                float p0 = exp2f(sf[mk][fq][0] * SCL - M[fq]);
                float p1 = exp2f(sf[mk][fq][1] * SCL - M[fq]);
                float p2 = exp2f(sf[mk][fq][2] * SCL - M[fq]);
                float p3 = exp2f(sf[mk][fq][3] * SCL - M[fq]);
                lloc += (p0 + p1) + (p2 + p3);
                uint2 pw; pw.x = pack2(p0, p1); pw.y = pack2(p2, p3);
                u32 off = ((u32)(row * 64 + mk * 32 + lk * 8)) ^ (((u32)(row & 7)) << 4);
                *reinterpret_cast<uint2*>(PsB + off) = pw;
            }
            L[fq] += lloc;
        }

        // O^T += V^T · P^T
        __builtin_amdgcn_s_setprio(1);
        {
            bf16x8 pb[2];
            #pragma unroll
            for (int fq = 0; fq < 2; fq++) {
                int row = qw + fq * 16 + li;
                u32 off = ((u32)(row * 64 + lk * 16)) ^ (((u32)(row & 7)) << 4);
                pb[fq] = *reinterpret_cast<const bf16x8*>(PsB + off);
            }
            #pragma unroll
            for (int ct = 0; ct < 16; ct++) {
                int vr = ct * 16 + li;
                u32 voff = (u32)(vr * 64) + (((u32)(lk * 16)) ^ (((u32)((vr >> 1) & 3)) << 4));
                bf16x8 va = *reinterpret_cast<const bf16x8*>(VsB + voff);
                acc[0][ct] = mfma16(va, pb[0], acc[0][ct]);
                acc[1][ct] = mfma16(va, pb[1], acc[1][ct]);
            }
        }
        __builtin_amdgcn_s_setprio(0);
        asm volatile("s_waitcnt lgkmcnt(0)" ::: "memory");
        __builtin_amdgcn_s_barrier();
    }

    // fold the deferred per-lane L partials across lk groups
    #pragma unroll
    for (int fq = 0; fq < 2; fq++) {
        L[fq] += __shfl_xor(L[fq], 16);
        L[fq] += __shfl_xor(L[fq], 32);
    }

    size_t obase = (size_t)(sp * 4 + b) * 4096 + n0;
    #pragma unroll
    for (int fq = 0; fq < 2; fq++) {
        int q = qw + fq * 16 + li;
        #pragma unroll
        for (int ct = 0; ct < 16; ct++) {
            uint2 ow;
            ow.x = pack2(acc[fq][ct][0], acc[fq][ct][1]);
            ow.y = pack2(acc[fq][ct][2], acc[fq][ct][3]);
            *reinterpret_cast<uint2*>(&Op[(obase + q) * 256 + ct * 16 + lk * 4]) = ow;
        }
    }
    if (lk == 0) {
        #pragma unroll
        for (int fq = 0; fq < 2; fq++) {
            float2 v; v.x = M[fq]; v.y = L[fq];
            ML[obase + qw + fq * 16 + li] = v;
        }
    }
}

// ---------------- merge split-KV partials -> ctx bf16 [b][4096][256] ----------------
__global__ __launch_bounds__(256) void k_merge(const u16* __restrict__ Op, const float2* __restrict__ ML,
                                               u16* __restrict__ ctx) {
    int wg = blockIdx.x;
    int t = threadIdx.x;
    int b = wg >> 12, q = wg & 4095;
    float2 ml[4];
    float Mx = -1e30f;
    #pragma unroll
    for (int s = 0; s < 4; s++) { ml[s] = ML[((size_t)(s * 4 + b) << 12) + q]; Mx = fmaxf(Mx, ml[s].x); }
    float Lt = 0.f, w[4];
    #pragma unroll
    for (int s = 0; s < 4; s++) { w[s] = exp2f(ml[s].x - Mx); Lt += ml[s].y * w[s]; }
    float inv = 1.f / Lt;
    float o = 0.f;
    #pragma unroll
    for (int s = 0; s < 4; s++)
        o += w[s] * bf2f(Op[((((size_t)(s * 4 + b) << 12) + q)) * 256 + t]);
    ctx[(((size_t)b << 12) + q) * 256 + t] = f2bf(o * inv);
}

extern "C" void kernel_launch(void* const* d_in, const int* in_sizes, int n_in,
                              void* d_out, int out_size, void* d_ws, size_t ws_size,
                              hipStream_t stream) {
    const void* x   = d_in[0];
    const void* qW1 = d_in[1];  const void* qg1 = d_in[2];  const void* qb1 = d_in[3];
    const void* qW2 = d_in[4];  const void* qg2 = d_in[5];  const void* qb2 = d_in[6];
    const void* kW1 = d_in[7];  const void* kg1 = d_in[8];  const void* kb1 = d_in[9];
    const void* kW2 = d_in[10]; const void* kg2 = d_in[11]; const void* kb2 = d_in[12];
    const void* vW  = d_in[13]; const void* vg  = d_in[14]; const void* vb  = d_in[15];
    const void* oW  = d_in[16]; const void* og  = d_in[17]; const void* ob  = d_in[18];

    char* ws = (char*)d_ws;
    int*   dflag = (int*)ws;
    float* xg = (float*)(ws + 4096);
    float* ck = (float*)(ws + 16384);
    float* cv = (float*)(ws + 20480);
    float* pg = (float*)(ws + 24576);
    u16* wb = (u16*)(ws + 40960);              // 655360 bf16 weights
    u16* qW1b = wb;
    u16* qW2b = wb + 131072;
    u16* kW1b = wb + 196608;
    u16* kW2b = wb + 327680;
    u16* vWb  = wb + 393216;
    u16* oWb  = wb + 524288;
    const size_t S = (size_t)4096 * 256;
    const size_t SLOT = 4 * S;
    u16* s0 = (u16*)(ws + 0x180000);
    u16* s1 = s0 + SLOT;
    u16* s2 = s1 + SLOT;
    u16* s3 = s2 + SLOT;
    float2* mlBuf = (float2*)s3;               // ML in s3 (free during attn)
    u16* xT = (u16*)d_out;                     // lower 16.8MB of d_out
    u16* k1buf = (u16*)d_out + 8388608;        // upper 16.8MB of d_out (free until attn)
    u16* opart = (u16*)d_out;                  // attn partials overwrite all of d_out
    u16* ctxBuf = s1;                          // ctx into s1 (Q dead after attn)

    k_detect<<<1, 256, 0, stream>>>((const u32*)x, dflag);
    k_mean<<<2048, 256, 0, stream>>>(x, dflag, xg);
    k_xpose<<<dim3(64, 8, 4), 256, 0, stream>>>(x, dflag, xT);
    k_consts<<<1024, 64, 0, stream>>>(kW1, vW, dflag, xg, ck, cv);
    k_wconv<<<2560, 256, 0, stream>>>(qW1, qW2, kW1, kW2, vW, oW, dflag, wb);
    k_pconv<<<14, 256, 0, stream>>>(qg1, qb1, qg2, qb2, kg1, kb1, kg2, kb2,
                                    vg, vb, og, ob, dflag, pg);

    const long XS = (long)4096 * 512;
    // fused q1 (xT->s0) + k1 (xT->k1buf, bias ck)
    k_gemm_pair<<<dim3(32, 2, 8), 256, 0, stream>>>(xT, xT, XS, 512,
        qW1b, kW1b, 512, s0, k1buf, (long)S, 256,
        pg + 0, pg + 256, nullptr, pg + 1024, pg + 1280, ck, 256, 512);
    // fused q2 (s0->s1) + k2 (k1buf->s2)
    k_gemm_pair<<<dim3(32, 2, 8), 256, 0, stream>>>(s0, k1buf, (long)S, 256,
        qW2b, kW2b, 256, s1, s2, (long)S, 256,
        pg + 512, pg + 768, nullptr, pg + 1536, pg + 1792, nullptr, 0, 256);
    // v (channel-major, bias cv) -> s0
    k_gemm_bt<true, u16><<<dim3(2, 32, 4), 256, 0, stream>>>(vWb, 0, 512, xT, XS, 512,
        s0, (long)S, 4096, pg + 2048, pg + 2304, cv, 256, 512);
    // attention (split-KV x4): Q(s1), K(s2), V(s0) -> partials in d_out, ML in s3
    k_attn<<<512, 256, 0, stream>>>(s1, s2, s0, opart, mlBuf);
    // merge -> ctx (s1)
    k_merge<<<16384, 256, 0, stream>>>(opart, mlBuf, ctxBuf);
    // out projection -> d_out as f32 [B][512][4096]
    k_gemm_bt<true, float><<<dim3(4, 32, 4), 256, 0, stream>>>(oWb, 0, 256, ctxBuf, (long)S, 256,
        (float*)d_out, (long)512 * 4096, 4096, pg + 2560, pg + 3072, nullptr, 0, 256);
}

// Round 14
// 215.749 us; speedup vs baseline: 2.0772x; 1.0486x over previous
//
#include <hip/hip_runtime.h>
#include <stdint.h>

typedef __bf16 bf16x8 __attribute__((ext_vector_type(8)));
typedef float f32x4 __attribute__((ext_vector_type(4)));
typedef unsigned short u16;
typedef uint32_t u32;

union V16 { uint4 v; u16 e[8]; };

__device__ __forceinline__ float bf2f(u16 h) {
    u32 u = ((u32)h) << 16; float f; __builtin_memcpy(&f, &u, 4); return f;
}
__device__ __forceinline__ u16 f2bf(float f) {
    u32 u; __builtin_memcpy(&u, &f, 4);
    u32 r = (u + 0x7FFFu + ((u >> 16) & 1u)) >> 16; return (u16)r;
}
__device__ __forceinline__ u32 cvtpk(float lo, float hi) {
    u32 r;
    asm("v_cvt_pk_bf16_f32 %0, %1, %2" : "=v"(r) : "v"(lo), "v"(hi));
    return r;
}
__device__ __forceinline__ f32x4 mfma16(bf16x8 a, bf16x8 b, f32x4 c) {
    return __builtin_amdgcn_mfma_f32_16x16x32_bf16(a, b, c, 0, 0, 0);
}
// async 16B global -> LDS (wave-uniform LDS base; HW adds lane*16)
__device__ __forceinline__ void gll16(const u16* g, u16* l) {
    __builtin_amdgcn_global_load_lds(
        (const __attribute__((address_space(1))) unsigned int*)g,
        (__attribute__((address_space(3))) unsigned int*)l, 16, 0, 0);
}
// flag: 0=bf16, 1=f32, 2=f64
__device__ __forceinline__ float loadElem(const void* p, size_t i, int fl) {
    if (fl == 1) return ((const float*)p)[i];
    if (fl == 2) return (float)((const double*)p)[i];
    return bf2f(((const u16*)p)[i]);
}

// ---------------- dtype detect on x ----------------
__global__ __launch_bounds__(256) void k_detect(const u32* __restrict__ xw, int* __restrict__ flag) {
    int t = threadIdx.x;
    int cA = 0, cB = 0;
    #pragma unroll
    for (int i = 0; i < 16; i++) {
        u32 w = xw[i * 256 + t];
        cA += (((w >> 23) & 0xFFu) >= 0xC0u) ? 1 : 0;
        cB += (((w >> 7)  & 0xFFu) >= 0xC0u) ? 1 : 0;
    }
    #pragma unroll
    for (int m = 32; m >= 1; m >>= 1) { cA += __shfl_xor(cA, m); cB += __shfl_xor(cB, m); }
    __shared__ int sA[4], sB[4];
    if ((t & 63) == 0) { sA[t >> 6] = cA; sB[t >> 6] = cB; }
    __syncthreads();
    if (t == 0) {
        int a = sA[0] + sA[1] + sA[2] + sA[3];
        int b = sB[0] + sB[1] + sB[2] + sB[3];
        *flag = (a > 64) ? 2 : ((b > 64) ? 1 : 0);
    }
}

// ---------------- transpose(+cast) x -> xT bf16, with per-block mean partials ----------------
// partial[(b*512 + c) * 64 + nblk] = sum over this block's 64 pixels of x[b][c][...]
__global__ __launch_bounds__(256) void k_xpose(const void* __restrict__ xv, const int* __restrict__ dt,
                                               u16* __restrict__ xT, float* __restrict__ partial) {
    __shared__ u16 tile[64][72];
    int b = blockIdx.z;
    int n0 = blockIdx.x * 64, c0 = blockIdx.y * 64;
    u16* xTb = xT + (size_t)b * 4096 * 512;
    int t = threadIdx.x;
    int fl = *dt;
    const size_t xbase = (size_t)b * 512 * 4096;
    if (fl == 1) {
        const float* xb = (const float*)xv + xbase;
        int cr = t >> 4, n4 = (t & 15) * 4;
        #pragma unroll
        for (int i = 0; i < 4; i++) {
            int c = cr + i * 16;
            float4 v = *reinterpret_cast<const float4*>(xb + (size_t)(c0 + c) * 4096 + n0 + n4);
            tile[n4 + 0][c] = f2bf(v.x); tile[n4 + 1][c] = f2bf(v.y);
            tile[n4 + 2][c] = f2bf(v.z); tile[n4 + 3][c] = f2bf(v.w);
            float s = (v.x + v.y) + (v.z + v.w);
            s += __shfl_xor(s, 1); s += __shfl_xor(s, 2);
            s += __shfl_xor(s, 4); s += __shfl_xor(s, 8);
            if ((t & 15) == 0)
                partial[((size_t)b * 512 + c0 + c) * 64 + blockIdx.x] = s;
        }
    } else {
        int c4 = t >> 6, n = t & 63;
        for (int i = 0; i < 16; i++) {
            int c = c4 + i * 4;
            float v = loadElem(xv, xbase + (size_t)(c0 + c) * 4096 + n0 + n, fl);
            tile[n][c] = f2bf(v);
            float s = v;
            #pragma unroll
            for (int m = 32; m >= 1; m >>= 1) s += __shfl_xor(s, m);
            if (n == 0)
                partial[((size_t)b * 512 + c0 + c) * 64 + blockIdx.x] = s;
        }
    }
    __syncthreads();
    int nr = t >> 3, c8 = (t & 7) * 8;
    #pragma unroll
    for (int i = 0; i < 2; i++) {
        int n = nr + i * 32;
        V16 v;
        #pragma unroll
        for (int j = 0; j < 8; j++) v.e[j] = tile[n][c8 + j];
        *reinterpret_cast<uint4*>(xTb + (size_t)(n0 + n) * 512 + c0 + c8) = v.v;
    }
}

// ---------------- reduce partials -> xg mean (deterministic) ----------------
__global__ __launch_bounds__(256) void k_mean2(const float* __restrict__ partial, float* __restrict__ xg) {
    int bc = blockIdx.x * 256 + threadIdx.x;   // 2048 = 4b x 512c
    const float* p = partial + (size_t)bc * 64;
    float s = 0.f;
    #pragma unroll
    for (int i = 0; i < 64; i++) s += p[i];
    xg[bc] = s * (1.f / 4096.f);
}

// ---------------- fold mean through kW1/vW cols [0,512): per-(b,o) f32 bias ----------------
__global__ __launch_bounds__(64) void k_consts(const void* __restrict__ kW1, const void* __restrict__ vW,
                                               const int* __restrict__ dt, const float* __restrict__ xg,
                                               float* __restrict__ ck, float* __restrict__ cv) {
    int bo = blockIdx.x; int b = bo >> 8; int o = bo & 255;
    int l = threadIdx.x;
    int fl = *dt;
    const float* g = xg + b * 512;
    float sk = 0.f, sv = 0.f;
    for (int c = l; c < 512; c += 64) {
        float xv = g[c];
        sk += loadElem(kW1, (size_t)o * 1024 + c, fl) * xv;
        sv += loadElem(vW,  (size_t)o * 1024 + c, fl) * xv;
    }
    #pragma unroll
    for (int m = 32; m >= 1; m >>= 1) { sk += __shfl_xor(sk, m); sv += __shfl_xor(sv, m); }
    if (l == 0) { ck[bo] = sk; cv[bo] = sv; }
}

// ---------------- weights -> bf16 into ws ----------------
__global__ __launch_bounds__(256) void k_wconv(const void* __restrict__ qW1, const void* __restrict__ qW2,
                                               const void* __restrict__ kW1, const void* __restrict__ kW2,
                                               const void* __restrict__ vW, const void* __restrict__ oW,
                                               const int* __restrict__ dt, u16* __restrict__ dst) {
    int i = blockIdx.x * 256 + threadIdx.x;
    int fl = *dt;
    const void* s; size_t so;
    if (i < 131072)      { s = qW1; so = (size_t)i; }
    else if (i < 196608) { int j = i - 131072; s = qW2; so = (size_t)j; }
    else if (i < 327680) { int j = i - 196608; s = kW1; so = (size_t)(j >> 9) * 1024 + 512 + (j & 511); }
    else if (i < 393216) { int j = i - 327680; s = kW2; so = (size_t)j; }
    else if (i < 524288) { int j = i - 393216; s = vW;  so = (size_t)(j >> 9) * 1024 + 512 + (j & 511); }
    else                 { int j = i - 524288; s = oW;  so = (size_t)j; }
    dst[i] = f2bf(loadElem(s, so, fl));
}

// ---------------- affine params -> f32 into ws ----------------
__global__ __launch_bounds__(256) void k_pconv(const void* qg1, const void* qb1, const void* qg2, const void* qb2,
                                               const void* kg1, const void* kb1, const void* kg2, const void* kb2,
                                               const void* vg, const void* vb, const void* og, const void* ob,
                                               const int* __restrict__ dt, float* __restrict__ pg) {
    int j = blockIdx.x * 256 + threadIdx.x;
    if (j >= 3584) return;
    int fl = *dt;
    const void* s; int o;
    if (j < 256)       { s = qg1; o = j; }
    else if (j < 512)  { s = qb1; o = j - 256; }
    else if (j < 768)  { s = qg2; o = j - 512; }
    else if (j < 1024) { s = qb2; o = j - 768; }
    else if (j < 1280) { s = kg1; o = j - 1024; }
    else if (j < 1536) { s = kb1; o = j - 1280; }
    else if (j < 1792) { s = kg2; o = j - 1536; }
    else if (j < 2048) { s = kb2; o = j - 1792; }
    else if (j < 2304) { s = vg;  o = j - 2048; }
    else if (j < 2560) { s = vb;  o = j - 2304; }
    else if (j < 3072) { s = og;  o = j - 2560; }
    else               { s = ob;  o = j - 3072; }
    pg[j] = loadElem(s, (size_t)o, fl);
}

// ---------------- gemm_bt v2 (out-proj): async dbuf via global_load_lds ----------------
template<bool AFF_ROW, typename OT>
__global__ __launch_bounds__(256) void k_gemm_bt(
    const u16* __restrict__ A, long aBS, int lda,
    const u16* __restrict__ Bm, long bBS, int ldb,
    OT* __restrict__ C, long cBS, int ldc,
    const float* __restrict__ gamma, const float* __restrict__ beta,
    const float* __restrict__ bias, int biasBS, int K) {
    __shared__ u16 As[2][128 * 64];
    __shared__ u16 Bs[2][128 * 64];
    int b = blockIdx.z;
    const u16* Ab = A + (size_t)b * aBS;
    const u16* Bb = Bm + (size_t)b * bBS;
    OT* Cb = C + (size_t)b * cBS;
    int m0 = blockIdx.x * 128, n0 = blockIdx.y * 128;
    int t = threadIdx.x;
    int lane = t & 63, wid = t >> 6;
    int wr = wid >> 1, wc = wid & 1;
    int li = lane & 15, lk = lane >> 4;

    f32x4 acc[4][4] = {};

    auto stage = [&](int k0, int buf) {
        #pragma unroll
        for (int j = 0; j < 4; j++) {
            int c = wid * 4 + j;
            u32 pl = (u32)c * 1024 + (u32)lane * 16;
            u32 r = pl >> 7;
            u32 q = (pl & 127) ^ ((r & 7) << 4);
            gll16(Ab + (size_t)(m0 + r) * lda + k0 + (q >> 1), &As[buf][0] + (c << 9));
            gll16(Bb + (size_t)(n0 + r) * ldb + k0 + (q >> 1), &Bs[buf][0] + (c << 9));
        }
    };

    const int nk = K >> 6;
    stage(0, 0);

    for (int kst = 0; kst < nk; kst++) {
        int cur = kst & 1;
        if (kst + 1 < nk) {
            stage((kst + 1) << 6, cur ^ 1);
            asm volatile("s_waitcnt vmcnt(8)" ::: "memory");
        } else {
            asm volatile("s_waitcnt vmcnt(0)" ::: "memory");
        }
        __builtin_amdgcn_sched_barrier(0);
        __builtin_amdgcn_s_barrier();

        const char* AsB = (const char*)&As[cur][0];
        const char* BsB = (const char*)&Bs[cur][0];
        #pragma unroll
        for (int ks = 0; ks < 2; ks++) {
            bf16x8 af[4], bfr[4];
            #pragma unroll
            for (int mi = 0; mi < 4; mi++) {
                int r = wr * 64 + mi * 16 + li;
                u32 off = ((u32)(r * 128 + (ks * 32 + lk * 8) * 2)) ^ (((u32)(r & 7)) << 4);
                af[mi] = *reinterpret_cast<const bf16x8*>(AsB + off);
            }
            #pragma unroll
            for (int ni = 0; ni < 4; ni++) {
                int r = wc * 64 + ni * 16 + li;
                u32 off = ((u32)(r * 128 + (ks * 32 + lk * 8) * 2)) ^ (((u32)(r & 7)) << 4);
                bfr[ni] = *reinterpret_cast<const bf16x8*>(BsB + off);
            }
            #pragma unroll
            for (int mi = 0; mi < 4; mi++)
                #pragma unroll
                for (int ni = 0; ni < 4; ni++)
                    acc[mi][ni] = mfma16(af[mi], bfr[ni], acc[mi][ni]);
        }
        asm volatile("s_waitcnt lgkmcnt(0)" ::: "memory");
        __builtin_amdgcn_s_barrier();
    }
    #pragma unroll
    for (int mi = 0; mi < 4; mi++) {
        #pragma unroll
        for (int ni = 0; ni < 4; ni++) {
            #pragma unroll
            for (int r = 0; r < 4; r++) {
                int m = m0 + wr * 64 + mi * 16 + lk * 4 + r;
                int n = n0 + wc * 64 + ni * 16 + li;
                int oc = AFF_ROW ? m : n;
                float v = acc[mi][ni][r];
                if (bias) v += bias[b * biasBS + oc];
                float y = v * gamma[oc] + beta[oc];
                y = fmaxf(y, 0.f);
                if constexpr (sizeof(OT) == 2) Cb[(size_t)m * ldc + n] = f2bf(y);
                else                           Cb[(size_t)m * ldc + n] = y;
            }
        }
    }
}

// ---------------- fused 3-op gemm: z = op*4 + b; op0=q1, op1=k1, op2=v (x/y roles swapped) ----------------
__global__ __launch_bounds__(256) void k_gemm_tri(
    const u16* __restrict__ xT, long xBS,
    const u16* __restrict__ Wq, const u16* __restrict__ Wk, const u16* __restrict__ Wv,
    u16* __restrict__ Cq, u16* __restrict__ Ck2, u16* __restrict__ Cv, long cBS,
    const float* __restrict__ pg, const float* __restrict__ ckb, const float* __restrict__ cvb) {
    __shared__ u16 As[2][128 * 64];
    __shared__ u16 Bs[2][128 * 64];
    int z = blockIdx.z;
    int op = z >> 2, b = z & 3;
    const u16* Ab; const u16* Bb; u16* Cb; int ldc;
    const float* gamma; const float* beta; const float* bias;
    int m0, n0;
    if (op == 2) {
        Ab = Wv; Bb = xT + (size_t)b * xBS; Cb = Cv + (size_t)b * cBS; ldc = 4096;
        gamma = pg + 2048; beta = pg + 2304; bias = cvb;
        m0 = blockIdx.y * 128; n0 = blockIdx.x * 128;
    } else if (op == 1) {
        Ab = xT + (size_t)b * xBS; Bb = Wk; Cb = Ck2 + (size_t)b * cBS; ldc = 256;
        gamma = pg + 1024; beta = pg + 1280; bias = ckb;
        m0 = blockIdx.x * 128; n0 = blockIdx.y * 128;
    } else {
        Ab = xT + (size_t)b * xBS; Bb = Wq; Cb = Cq + (size_t)b * cBS; ldc = 256;
        gamma = pg + 0; beta = pg + 256; bias = nullptr;
        m0 = blockIdx.x * 128; n0 = blockIdx.y * 128;
    }
    int t = threadIdx.x;
    int lane = t & 63, wid = t >> 6;
    int wr = wid >> 1, wc = wid & 1;
    int li = lane & 15, lk = lane >> 4;

    f32x4 acc[4][4] = {};

    auto stage = [&](int k0, int buf) {
        #pragma unroll
        for (int j = 0; j < 4; j++) {
            int c = wid * 4 + j;
            u32 pl = (u32)c * 1024 + (u32)lane * 16;
            u32 r = pl >> 7;
            u32 q = (pl & 127) ^ ((r & 7) << 4);
            gll16(Ab + (size_t)(m0 + r) * 512 + k0 + (q >> 1), &As[buf][0] + (c << 9));
            gll16(Bb + (size_t)(n0 + r) * 512 + k0 + (q >> 1), &Bs[buf][0] + (c << 9));
        }
    };

    stage(0, 0);

    for (int kst = 0; kst < 8; kst++) {
        int cur = kst & 1;
        if (kst + 1 < 8) {
            stage((kst + 1) << 6, cur ^ 1);
            asm volatile("s_waitcnt vmcnt(8)" ::: "memory");
        } else {
            asm volatile("s_waitcnt vmcnt(0)" ::: "memory");
        }
        __builtin_amdgcn_sched_barrier(0);
        __builtin_amdgcn_s_barrier();

        const char* AsB = (const char*)&As[cur][0];
        const char* BsB = (const char*)&Bs[cur][0];
        #pragma unroll
        for (int ks = 0; ks < 2; ks++) {
            bf16x8 af[4], bfr[4];
            #pragma unroll
            for (int mi = 0; mi < 4; mi++) {
                int r = wr * 64 + mi * 16 + li;
                u32 off = ((u32)(r * 128 + (ks * 32 + lk * 8) * 2)) ^ (((u32)(r & 7)) << 4);
                af[mi] = *reinterpret_cast<const bf16x8*>(AsB + off);
            }
            #pragma unroll
            for (int ni = 0; ni < 4; ni++) {
                int r = wc * 64 + ni * 16 + li;
                u32 off = ((u32)(r * 128 + (ks * 32 + lk * 8) * 2)) ^ (((u32)(r & 7)) << 4);
                bfr[ni] = *reinterpret_cast<const bf16x8*>(BsB + off);
            }
            #pragma unroll
            for (int mi = 0; mi < 4; mi++)
                #pragma unroll
                for (int ni = 0; ni < 4; ni++)
                    acc[mi][ni] = mfma16(af[mi], bfr[ni], acc[mi][ni]);
        }
        asm volatile("s_waitcnt lgkmcnt(0)" ::: "memory");
        __builtin_amdgcn_s_barrier();
    }
    #pragma unroll
    for (int mi = 0; mi < 4; mi++) {
        #pragma unroll
        for (int ni = 0; ni < 4; ni++) {
            #pragma unroll
            for (int r = 0; r < 4; r++) {
                int m = m0 + wr * 64 + mi * 16 + lk * 4 + r;
                int n = n0 + wc * 64 + ni * 16 + li;
                int oc = (op == 2) ? m : n;
                float v = acc[mi][ni][r];
                if (bias) v += bias[b * 256 + oc];
                float y = v * gamma[oc] + beta[oc];
                y = fmaxf(y, 0.f);
                Cb[(size_t)m * ldc + n] = f2bf(y);
            }
        }
    }
}

// ---------------- fused pair gemm (q2+k2): blockIdx.z = op*4 + b ----------------
__global__ __launch_bounds__(256) void k_gemm_pair(
    const u16* __restrict__ A0, const u16* __restrict__ A1, long aBS, int lda,
    const u16* __restrict__ B0, const u16* __restrict__ B1, int ldb,
    u16* __restrict__ C0, u16* __restrict__ C1, long cBS, int ldc,
    const float* __restrict__ g0, const float* __restrict__ be0,
    const float* __restrict__ g1, const float* __restrict__ be1, int K) {
    __shared__ u16 As[2][128 * 64];
    __shared__ u16 Bs[2][128 * 64];
    int z = blockIdx.z;
    int op = z >> 2, b = z & 3;
    const u16* Ab = (op ? A1 : A0) + (size_t)b * aBS;
    const u16* Bb = op ? B1 : B0;
    u16* Cb = (op ? C1 : C0) + (size_t)b * cBS;
    const float* gamma = op ? g1 : g0;
    const float* beta  = op ? be1 : be0;
    int m0 = blockIdx.x * 128, n0 = blockIdx.y * 128;
    int t = threadIdx.x;
    int lane = t & 63, wid = t >> 6;
    int wr = wid >> 1, wc = wid & 1;
    int li = lane & 15, lk = lane >> 4;

    f32x4 acc[4][4] = {};

    auto stage = [&](int k0, int buf) {
        #pragma unroll
        for (int j = 0; j < 4; j++) {
            int c = wid * 4 + j;
            u32 pl = (u32)c * 1024 + (u32)lane * 16;
            u32 r = pl >> 7;
            u32 q = (pl & 127) ^ ((r & 7) << 4);
            gll16(Ab + (size_t)(m0 + r) * lda + k0 + (q >> 1), &As[buf][0] + (c << 9));
            gll16(Bb + (size_t)(n0 + r) * ldb + k0 + (q >> 1), &Bs[buf][0] + (c << 9));
        }
    };

    const int nk = K >> 6;
    stage(0, 0);

    for (int kst = 0; kst < nk; kst++) {
        int cur = kst & 1;
        if (kst + 1 < nk) {
            stage((kst + 1) << 6, cur ^ 1);
            asm volatile("s_waitcnt vmcnt(8)" ::: "memory");
        } else {
            asm volatile("s_waitcnt vmcnt(0)" ::: "memory");
        }
        __builtin_amdgcn_sched_barrier(0);
        __builtin_amdgcn_s_barrier();

        const char* AsB = (const char*)&As[cur][0];
        const char* BsB = (const char*)&Bs[cur][0];
        #pragma unroll
        for (int ks = 0; ks < 2; ks++) {
            bf16x8 af[4], bfr[4];
            #pragma unroll
            for (int mi = 0; mi < 4; mi++) {
                int r = wr * 64 + mi * 16 + li;
                u32 off = ((u32)(r * 128 + (ks * 32 + lk * 8) * 2)) ^ (((u32)(r & 7)) << 4);
                af[mi] = *reinterpret_cast<const bf16x8*>(AsB + off);
            }
            #pragma unroll
            for (int ni = 0; ni < 4; ni++) {
                int r = wc * 64 + ni * 16 + li;
                u32 off = ((u32)(r * 128 + (ks * 32 + lk * 8) * 2)) ^ (((u32)(r & 7)) << 4);
                bfr[ni] = *reinterpret_cast<const bf16x8*>(BsB + off);
            }
            #pragma unroll
            for (int mi = 0; mi < 4; mi++)
                #pragma unroll
                for (int ni = 0; ni < 4; ni++)
                    acc[mi][ni] = mfma16(af[mi], bfr[ni], acc[mi][ni]);
        }
        asm volatile("s_waitcnt lgkmcnt(0)" ::: "memory");
        __builtin_amdgcn_s_barrier();
    }
    #pragma unroll
    for (int mi = 0; mi < 4; mi++) {
        #pragma unroll
        for (int ni = 0; ni < 4; ni++) {
            #pragma unroll
            for (int r = 0; r < 4; r++) {
                int m = m0 + wr * 64 + mi * 16 + lk * 4 + r;
                int n = n0 + wc * 64 + ni * 16 + li;
                float v = acc[mi][ni][r];
                float y = v * gamma[n] + beta[n];
                y = fmaxf(y, 0.f);
                Cb[(size_t)m * ldc + n] = f2bf(y);
            }
        }
    }
}

// ---------------- flash attention v7: swapped QK^T + async dbuf + lane-local softmax + cvt_pk ----------------
__global__ __launch_bounds__(256, 2) void k_attn(const u16* __restrict__ Q, const u16* __restrict__ Kt,
                                                 const u16* __restrict__ V, u16* __restrict__ Op,
                                                 float2* __restrict__ ML) {
    __shared__ u16 Ks[2][32 * 256];
    __shared__ u16 Vs[2][256 * 32];
    __shared__ u16 Ps[128 * 32];
    char* PsB = (char*)Ps;
    int wg = blockIdx.x;
    int bs = wg & 15, qt = wg >> 4;
    int b = bs >> 2, sp = bs & 3;
    int n0 = qt * 128;
    int k0 = sp * 1024;
    const size_t S = (size_t)4096 * 256;
    const u16* Qb = Q + (size_t)b * S + (size_t)n0 * 256;
    const u16* Kb = Kt + (size_t)b * S + (size_t)k0 * 256;
    const u16* Vb = V + (size_t)b * S + k0;      // channel-major [256][4096]
    int t = threadIdx.x;
    int lane = t & 63, wid = t >> 6;
    int li = lane & 15, lk = lane >> 4;
    int qw = wid * 32;

    bf16x8 qf[2][8];
    #pragma unroll
    for (int fq = 0; fq < 2; fq++)
        #pragma unroll
        for (int kc = 0; kc < 8; kc++)
            qf[fq][kc] = *reinterpret_cast<const bf16x8*>(Qb + (size_t)(qw + fq * 16 + li) * 256 + kc * 32 + lk * 8);

    f32x4 acc[2][16] = {};
    float M[2] = {-1e30f, -1e30f};
    float L[2] = {0.f, 0.f};
    const float SCL = 0.0625f * 1.44269504088896f;

    auto stage = [&](int kt, int buf) {
        const u16* Kp = Kb + (size_t)kt * 32 * 256;
        const u16* Vp = Vb + kt * 32;
        u16* Kd = &Ks[buf][0];
        u16* Vd = &Vs[buf][0];
        #pragma unroll
        for (int j = 0; j < 4; j++) {
            int c = wid * 4 + j;
            u32 pl = (u32)c * 1024 + (u32)lane * 16;
            u32 krow = pl >> 9;
            u32 kq = (pl & 511) ^ ((krow & 7) << 4);
            gll16(Kp + krow * 256 + (kq >> 1), Kd + (c << 9));
            u32 vcc = pl >> 6;
            u32 vq = (pl & 63) ^ (((vcc >> 1) & 3) << 4);
            gll16(Vp + (size_t)vcc * 4096 + (vq >> 1), Vd + (c << 9));
        }
    };

    stage(0, 0);

    for (int kt = 0; kt < 32; kt++) {
        int cur = kt & 1;
        if (kt + 1 < 32) {
            stage(kt + 1, cur ^ 1);
            asm volatile("s_waitcnt vmcnt(8)" ::: "memory");
        } else {
            asm volatile("s_waitcnt vmcnt(0)" ::: "memory");
        }
        __builtin_amdgcn_sched_barrier(0);
        __builtin_amdgcn_s_barrier();

        const char* KsB = (const char*)&Ks[cur][0];
        const char* VsB = (const char*)&Vs[cur][0];

        // S^T = K · Q
        __builtin_amdgcn_s_setprio(1);
        f32x4 sf[2][2] = {};
        #pragma unroll
        for (int mk = 0; mk < 2; mk++) {
            #pragma unroll
            for (int kc = 0; kc < 8; kc++) {
                int row = mk * 16 + li;
                u32 off = (u32)(row * 512) + (((u32)(kc * 64 + lk * 16)) ^ (((u32)(row & 7)) << 4));
                bf16x8 kb = *reinterpret_cast<const bf16x8*>(KsB + off);
                sf[mk][0] = mfma16(kb, qf[0][kc], sf[mk][0]);
                sf[mk][1] = mfma16(kb, qf[1][kc], sf[mk][1]);
            }
        }
        __builtin_amdgcn_s_setprio(0);

        // lane-local max guard: cross-lane ops only in the rare rescale branch
        float lm[2];
        #pragma unroll
        for (int fq = 0; fq < 2; fq++) {
            lm[fq] = fmaxf(fmaxf(fmaxf(sf[0][fq][0], sf[0][fq][1]), fmaxf(sf[0][fq][2], sf[0][fq][3])),
                           fmaxf(fmaxf(sf[1][fq][0], sf[1][fq][1]), fmaxf(sf[1][fq][2], sf[1][fq][3]))) * SCL;
        }
        bool ok = (lm[0] <= M[0] + 24.f) && (lm[1] <= M[1] + 24.f);
        if (!__all(ok ? 1 : 0)) {
            #pragma unroll
            for (int fq = 0; fq < 2; fq++) {
                float mx = lm[fq];
                mx = fmaxf(mx, __shfl_xor(mx, 16));
                mx = fmaxf(mx, __shfl_xor(mx, 32));
                float nM = fmaxf(M[fq], mx);
                float rs = exp2f(M[fq] - nM);
                L[fq] *= rs; M[fq] = nM;
                #pragma unroll
                for (int ct = 0; ct < 16; ct++) {
                    acc[fq][ct][0] *= rs; acc[fq][ct][1] *= rs;
                    acc[fq][ct][2] *= rs; acc[fq][ct][3] *= rs;
                }
            }
        }
        #pragma unroll
        for (int fq = 0; fq < 2; fq++) {
            int row = qw + fq * 16 + li;
            float lloc = 0.f;
            #pragma unroll
            for (int mk = 0; mk < 2; mk++) {
                float p0 = exp2f(sf[mk][fq][0] * SCL - M[fq]);
                float p1 = exp2f(sf[mk][fq][1] * SCL - M[fq]);
                float p2 = exp2f(sf[mk][fq][2] * SCL - M[fq]);
                float p3 = exp2f(sf[mk][fq][3] * SCL - M[fq]);
                lloc += (p0 + p1) + (p2 + p3);
                uint2 pw; pw.x = cvtpk(p0, p1); pw.y = cvtpk(p2, p3);
                u32 off = ((u32)(row * 64 + mk * 32 + lk * 8)) ^ (((u32)(row & 7)) << 4);
                *reinterpret_cast<uint2*>(PsB + off) = pw;
            }
            L[fq] += lloc;
        }

        // O^T += V^T · P^T
        __builtin_amdgcn_s_setprio(1);
        {
            bf16x8 pb[2];
            #pragma unroll
            for (int fq = 0; fq < 2; fq++) {
                int row = qw + fq * 16 + li;
                u32 off = ((u32)(row * 64 + lk * 16)) ^ (((u32)(row & 7)) << 4);
                pb[fq] = *reinterpret_cast<const bf16x8*>(PsB + off);
            }
            #pragma unroll
            for (int ct = 0; ct < 16; ct++) {
                int vr = ct * 16 + li;
                u32 voff = (u32)(vr * 64) + (((u32)(lk * 16)) ^ (((u32)((vr >> 1) & 3)) << 4));
                bf16x8 va = *reinterpret_cast<const bf16x8*>(VsB + voff);
                acc[0][ct] = mfma16(va, pb[0], acc[0][ct]);
                acc[1][ct] = mfma16(va, pb[1], acc[1][ct]);
            }
        }
        __builtin_amdgcn_s_setprio(0);
        asm volatile("s_waitcnt lgkmcnt(0)" ::: "memory");
        __builtin_amdgcn_s_barrier();
    }

    #pragma unroll
    for (int fq = 0; fq < 2; fq++) {
        L[fq] += __shfl_xor(L[fq], 16);
        L[fq] += __shfl_xor(L[fq], 32);
    }

    size_t obase = (size_t)(sp * 4 + b) * 4096 + n0;
    #pragma unroll
    for (int fq = 0; fq < 2; fq++) {
        int q = qw + fq * 16 + li;
        #pragma unroll
        for (int ct = 0; ct < 16; ct++) {
            uint2 ow;
            ow.x = cvtpk(acc[fq][ct][0], acc[fq][ct][1]);
            ow.y = cvtpk(acc[fq][ct][2], acc[fq][ct][3]);
            *reinterpret_cast<uint2*>(&Op[(obase + q) * 256 + ct * 16 + lk * 4]) = ow;
        }
    }
    if (lk == 0) {
        #pragma unroll
        for (int fq = 0; fq < 2; fq++) {
            float2 v; v.x = M[fq]; v.y = L[fq];
            ML[obase + qw + fq * 16 + li] = v;
        }
    }
}

// ---------------- merge split-KV partials -> ctx bf16 [b][4096][256] ----------------
__global__ __launch_bounds__(256) void k_merge(const u16* __restrict__ Op, const float2* __restrict__ ML,
                                               u16* __restrict__ ctx) {
    int wg = blockIdx.x;
    int t = threadIdx.x;
    int b = wg >> 12, q = wg & 4095;
    float2 ml[4];
    float Mx = -1e30f;
    #pragma unroll
    for (int s = 0; s < 4; s++) { ml[s] = ML[((size_t)(s * 4 + b) << 12) + q]; Mx = fmaxf(Mx, ml[s].x); }
    float Lt = 0.f, w[4];
    #pragma unroll
    for (int s = 0; s < 4; s++) { w[s] = exp2f(ml[s].x - Mx); Lt += ml[s].y * w[s]; }
    float inv = 1.f / Lt;
    float o = 0.f;
    #pragma unroll
    for (int s = 0; s < 4; s++)
        o += w[s] * bf2f(Op[((((size_t)(s * 4 + b) << 12) + q)) * 256 + t]);
    ctx[(((size_t)b << 12) + q) * 256 + t] = f2bf(o * inv);
}

extern "C" void kernel_launch(void* const* d_in, const int* in_sizes, int n_in,
                              void* d_out, int out_size, void* d_ws, size_t ws_size,
                              hipStream_t stream) {
    const void* x   = d_in[0];
    const void* qW1 = d_in[1];  const void* qg1 = d_in[2];  const void* qb1 = d_in[3];
    const void* qW2 = d_in[4];  const void* qg2 = d_in[5];  const void* qb2 = d_in[6];
    const void* kW1 = d_in[7];  const void* kg1 = d_in[8];  const void* kb1 = d_in[9];
    const void* kW2 = d_in[10]; const void* kg2 = d_in[11]; const void* kb2 = d_in[12];
    const void* vW  = d_in[13]; const void* vg  = d_in[14]; const void* vb  = d_in[15];
    const void* oW  = d_in[16]; const void* og  = d_in[17]; const void* ob  = d_in[18];

    char* ws = (char*)d_ws;
    int*   dflag = (int*)ws;
    float* xg = (float*)(ws + 4096);           // 2048 f32 means
    float* ck = (float*)(ws + 16384);
    float* cv = (float*)(ws + 20480);
    float* pg = (float*)(ws + 24576);
    u16* wb = (u16*)(ws + 40960);              // 655360 bf16 weights, ends at 1,351,680
    u16* qW1b = wb;
    u16* qW2b = wb + 131072;
    u16* kW1b = wb + 196608;
    u16* kW2b = wb + 327680;
    u16* vWb  = wb + 393216;
    u16* oWb  = wb + 524288;
    float* partials = (float*)(ws + 0x180000); // 4*512*64 f32 = 512KB
    float2* mlBuf = (float2*)(ws + 0x200000);  // 16*4096 float2 = 512KB
    const size_t S = (size_t)4096 * 256;
    const size_t SLOT = 4 * S;
    u16* s0 = (u16*)(ws + 0x280000);           // slots at 2.5MB; end ≈ 36.1MB
    u16* s1 = s0 + SLOT;
    u16* s2 = s1 + SLOT;
    u16* s3 = s2 + SLOT;
    u16* xT = (u16*)d_out;                     // lower 16.8MB of d_out
    u16* k1buf = (u16*)d_out + 8388608;        // upper 16.8MB of d_out
    u16* opart = (u16*)d_out;                  // attn partials overwrite all of d_out
    u16* ctxBuf = s1;                          // ctx into s1 (Q dead after attn)

    k_detect<<<1, 256, 0, stream>>>((const u32*)x, dflag);
    k_xpose<<<dim3(64, 8, 4), 256, 0, stream>>>(x, dflag, xT, partials);
    k_mean2<<<8, 256, 0, stream>>>(partials, xg);
    k_consts<<<1024, 64, 0, stream>>>(kW1, vW, dflag, xg, ck, cv);
    k_wconv<<<2560, 256, 0, stream>>>(qW1, qW2, kW1, kW2, vW, oW, dflag, wb);
    k_pconv<<<14, 256, 0, stream>>>(qg1, qb1, qg2, qb2, kg1, kb1, kg2, kb2,
                                    vg, vb, og, ob, dflag, pg);

    const long XS = (long)4096 * 512;
    // fused q1 (xT->s0) + k1 (xT->k1buf, bias ck) + v (vW x xT -> s3 channel-major, bias cv)
    k_gemm_tri<<<dim3(32, 2, 12), 256, 0, stream>>>(xT, XS, qW1b, kW1b, vWb,
        s0, k1buf, s3, (long)S, pg, ck, cv);
    // fused q2 (s0->s1) + k2 (k1buf->s2)
    k_gemm_pair<<<dim3(32, 2, 8), 256, 0, stream>>>(s0, k1buf, (long)S, 256,
        qW2b, kW2b, 256, s1, s2, (long)S, 256,
        pg + 512, pg + 768, pg + 1536, pg + 1792, 256);
    // attention (split-KV x4): Q(s1), K(s2), V(s3) -> partials in d_out, ML
    k_attn<<<512, 256, 0, stream>>>(s1, s2, s3, opart, mlBuf);
    // merge -> ctx (s1)
    k_merge<<<16384, 256, 0, stream>>>(opart, mlBuf, ctxBuf);
    // out projection -> d_out as f32 [B][512][4096]
    k_gemm_bt<true, float><<<dim3(4, 32, 4), 256, 0, stream>>>(oWb, 0, 256, ctxBuf, (long)S, 256,
        (float*)d_out, (long)512 * 4096, 4096, pg + 2560, pg + 3072, nullptr, 0, 256);
}

// Round 15
// 200.157 us; speedup vs baseline: 2.2390x; 1.0779x over previous
//
#include <hip/hip_runtime.h>
#include <stdint.h>

typedef __bf16 bf16x8 __attribute__((ext_vector_type(8)));
typedef float f32x4 __attribute__((ext_vector_type(4)));
typedef unsigned short u16;
typedef uint32_t u32;

union V16 { uint4 v; u16 e[8]; };
union BF8 { uint4 u; bf16x8 v; };

__device__ __forceinline__ float bf2f(u16 h) {
    u32 u = ((u32)h) << 16; float f; __builtin_memcpy(&f, &u, 4); return f;
}
__device__ __forceinline__ u16 f2bf(float f) {
    u32 u; __builtin_memcpy(&u, &f, 4);
    u32 r = (u + 0x7FFFu + ((u >> 16) & 1u)) >> 16; return (u16)r;
}
__device__ __forceinline__ u32 cvtpk(float lo, float hi) {
    u32 r;
    asm("v_cvt_pk_bf16_f32 %0, %1, %2" : "=v"(r) : "v"(lo), "v"(hi));
    return r;
}
__device__ __forceinline__ f32x4 mfma16(bf16x8 a, bf16x8 b, f32x4 c) {
    return __builtin_amdgcn_mfma_f32_16x16x32_bf16(a, b, c, 0, 0, 0);
}
// async 16B global -> LDS (wave-uniform LDS base; HW adds lane*16)
__device__ __forceinline__ void gll16(const u16* g, u16* l) {
    __builtin_amdgcn_global_load_lds(
        (const __attribute__((address_space(1))) unsigned int*)g,
        (__attribute__((address_space(3))) unsigned int*)l, 16, 0, 0);
}
// flag: 0=bf16, 1=f32, 2=f64
__device__ __forceinline__ float loadElem(const void* p, size_t i, int fl) {
    if (fl == 1) return ((const float*)p)[i];
    if (fl == 2) return (float)((const double*)p)[i];
    return bf2f(((const u16*)p)[i]);
}

// ---------------- dtype detect on x ----------------
__global__ __launch_bounds__(256) void k_detect(const u32* __restrict__ xw, int* __restrict__ flag) {
    int t = threadIdx.x;
    int cA = 0, cB = 0;
    #pragma unroll
    for (int i = 0; i < 16; i++) {
        u32 w = xw[i * 256 + t];
        cA += (((w >> 23) & 0xFFu) >= 0xC0u) ? 1 : 0;
        cB += (((w >> 7)  & 0xFFu) >= 0xC0u) ? 1 : 0;
    }
    #pragma unroll
    for (int m = 32; m >= 1; m >>= 1) { cA += __shfl_xor(cA, m); cB += __shfl_xor(cB, m); }
    __shared__ int sA[4], sB[4];
    if ((t & 63) == 0) { sA[t >> 6] = cA; sB[t >> 6] = cB; }
    __syncthreads();
    if (t == 0) {
        int a = sA[0] + sA[1] + sA[2] + sA[3];
        int b = sB[0] + sB[1] + sB[2] + sB[3];
        *flag = (a > 64) ? 2 : ((b > 64) ? 1 : 0);
    }
}

// ---------------- transpose(+cast) x -> xT bf16, with per-block mean partials ----------------
__global__ __launch_bounds__(256) void k_xpose(const void* __restrict__ xv, const int* __restrict__ dt,
                                               u16* __restrict__ xT, float* __restrict__ partial) {
    __shared__ u16 tile[64][72];
    int b = blockIdx.z;
    int n0 = blockIdx.x * 64, c0 = blockIdx.y * 64;
    u16* xTb = xT + (size_t)b * 4096 * 512;
    int t = threadIdx.x;
    int fl = *dt;
    const size_t xbase = (size_t)b * 512 * 4096;
    if (fl == 1) {
        const float* xb = (const float*)xv + xbase;
        int cr = t >> 4, n4 = (t & 15) * 4;
        #pragma unroll
        for (int i = 0; i < 4; i++) {
            int c = cr + i * 16;
            float4 v = *reinterpret_cast<const float4*>(xb + (size_t)(c0 + c) * 4096 + n0 + n4);
            tile[n4 + 0][c] = f2bf(v.x); tile[n4 + 1][c] = f2bf(v.y);
            tile[n4 + 2][c] = f2bf(v.z); tile[n4 + 3][c] = f2bf(v.w);
            float s = (v.x + v.y) + (v.z + v.w);
            s += __shfl_xor(s, 1); s += __shfl_xor(s, 2);
            s += __shfl_xor(s, 4); s += __shfl_xor(s, 8);
            if ((t & 15) == 0)
                partial[((size_t)b * 512 + c0 + c) * 64 + blockIdx.x] = s;
        }
    } else {
        int c4 = t >> 6, n = t & 63;
        for (int i = 0; i < 16; i++) {
            int c = c4 + i * 4;
            float v = loadElem(xv, xbase + (size_t)(c0 + c) * 4096 + n0 + n, fl);
            tile[n][c] = f2bf(v);
            float s = v;
            #pragma unroll
            for (int m = 32; m >= 1; m >>= 1) s += __shfl_xor(s, m);
            if (n == 0)
                partial[((size_t)b * 512 + c0 + c) * 64 + blockIdx.x] = s;
        }
    }
    __syncthreads();
    int nr = t >> 3, c8 = (t & 7) * 8;
    #pragma unroll
    for (int i = 0; i < 2; i++) {
        int n = nr + i * 32;
        V16 v;
        #pragma unroll
        for (int j = 0; j < 8; j++) v.e[j] = tile[n][c8 + j];
        *reinterpret_cast<uint4*>(xTb + (size_t)(n0 + n) * 512 + c0 + c8) = v.v;
    }
}

// ---------------- reduce partials -> xg mean (deterministic) ----------------
__global__ __launch_bounds__(256) void k_mean2(const float* __restrict__ partial, float* __restrict__ xg) {
    int bc = blockIdx.x * 256 + threadIdx.x;
    const float* p = partial + (size_t)bc * 64;
    float s = 0.f;
    #pragma unroll
    for (int i = 0; i < 64; i++) s += p[i];
    xg[bc] = s * (1.f / 4096.f);
}

// ---------------- fold mean through kW1/vW cols [0,512): per-(b,o) f32 bias ----------------
__global__ __launch_bounds__(64) void k_consts(const void* __restrict__ kW1, const void* __restrict__ vW,
                                               const int* __restrict__ dt, const float* __restrict__ xg,
                                               float* __restrict__ ck, float* __restrict__ cv) {
    int bo = blockIdx.x; int b = bo >> 8; int o = bo & 255;
    int l = threadIdx.x;
    int fl = *dt;
    const float* g = xg + b * 512;
    float sk = 0.f, sv = 0.f;
    for (int c = l; c < 512; c += 64) {
        float xv = g[c];
        sk += loadElem(kW1, (size_t)o * 1024 + c, fl) * xv;
        sv += loadElem(vW,  (size_t)o * 1024 + c, fl) * xv;
    }
    #pragma unroll
    for (int m = 32; m >= 1; m >>= 1) { sk += __shfl_xor(sk, m); sv += __shfl_xor(sv, m); }
    if (l == 0) { ck[bo] = sk; cv[bo] = sv; }
}

// ---------------- weights -> bf16 into ws ----------------
__global__ __launch_bounds__(256) void k_wconv(const void* __restrict__ qW1, const void* __restrict__ qW2,
                                               const void* __restrict__ kW1, const void* __restrict__ kW2,
                                               const void* __restrict__ vW, const void* __restrict__ oW,
                                               const int* __restrict__ dt, u16* __restrict__ dst) {
    int i = blockIdx.x * 256 + threadIdx.x;
    int fl = *dt;
    const void* s; size_t so;
    if (i < 131072)      { s = qW1; so = (size_t)i; }
    else if (i < 196608) { int j = i - 131072; s = qW2; so = (size_t)j; }
    else if (i < 327680) { int j = i - 196608; s = kW1; so = (size_t)(j >> 9) * 1024 + 512 + (j & 511); }
    else if (i < 393216) { int j = i - 327680; s = kW2; so = (size_t)j; }
    else if (i < 524288) { int j = i - 393216; s = vW;  so = (size_t)(j >> 9) * 1024 + 512 + (j & 511); }
    else                 { int j = i - 524288; s = oW;  so = (size_t)j; }
    dst[i] = f2bf(loadElem(s, so, fl));
}

// ---------------- affine params -> f32 into ws ----------------
__global__ __launch_bounds__(256) void k_pconv(const void* qg1, const void* qb1, const void* qg2, const void* qb2,
                                               const void* kg1, const void* kb1, const void* kg2, const void* kb2,
                                               const void* vg, const void* vb, const void* og, const void* ob,
                                               const int* __restrict__ dt, float* __restrict__ pg) {
    int j = blockIdx.x * 256 + threadIdx.x;
    if (j >= 3584) return;
    int fl = *dt;
    const void* s; int o;
    if (j < 256)       { s = qg1; o = j; }
    else if (j < 512)  { s = qb1; o = j - 256; }
    else if (j < 768)  { s = qg2; o = j - 512; }
    else if (j < 1024) { s = qb2; o = j - 768; }
    else if (j < 1280) { s = kg1; o = j - 1024; }
    else if (j < 1536) { s = kb1; o = j - 1280; }
    else if (j < 1792) { s = kg2; o = j - 1536; }
    else if (j < 2048) { s = kb2; o = j - 1792; }
    else if (j < 2304) { s = vg;  o = j - 2048; }
    else if (j < 2560) { s = vb;  o = j - 2304; }
    else if (j < 3072) { s = og;  o = j - 2560; }
    else               { s = ob;  o = j - 3072; }
    pg[j] = loadElem(s, (size_t)o, fl);
}

// ---------------- gemm_bt v2 (out-proj): async dbuf via global_load_lds ----------------
template<bool AFF_ROW, typename OT>
__global__ __launch_bounds__(256) void k_gemm_bt(
    const u16* __restrict__ A, long aBS, int lda,
    const u16* __restrict__ Bm, long bBS, int ldb,
    OT* __restrict__ C, long cBS, int ldc,
    const float* __restrict__ gamma, const float* __restrict__ beta,
    const float* __restrict__ bias, int biasBS, int K) {
    __shared__ u16 As[2][128 * 64];
    __shared__ u16 Bs[2][128 * 64];
    int b = blockIdx.z;
    const u16* Ab = A + (size_t)b * aBS;
    const u16* Bb = Bm + (size_t)b * bBS;
    OT* Cb = C + (size_t)b * cBS;
    int m0 = blockIdx.x * 128, n0 = blockIdx.y * 128;
    int t = threadIdx.x;
    int lane = t & 63, wid = t >> 6;
    int wr = wid >> 1, wc = wid & 1;
    int li = lane & 15, lk = lane >> 4;

    f32x4 acc[4][4] = {};

    auto stage = [&](int k0, int buf) {
        #pragma unroll
        for (int j = 0; j < 4; j++) {
            int c = wid * 4 + j;
            u32 pl = (u32)c * 1024 + (u32)lane * 16;
            u32 r = pl >> 7;
            u32 q = (pl & 127) ^ ((r & 7) << 4);
            gll16(Ab + (size_t)(m0 + r) * lda + k0 + (q >> 1), &As[buf][0] + (c << 9));
            gll16(Bb + (size_t)(n0 + r) * ldb + k0 + (q >> 1), &Bs[buf][0] + (c << 9));
        }
    };

    const int nk = K >> 6;
    stage(0, 0);

    for (int kst = 0; kst < nk; kst++) {
        int cur = kst & 1;
        if (kst + 1 < nk) {
            stage((kst + 1) << 6, cur ^ 1);
            asm volatile("s_waitcnt vmcnt(8)" ::: "memory");
        } else {
            asm volatile("s_waitcnt vmcnt(0)" ::: "memory");
        }
        __builtin_amdgcn_sched_barrier(0);
        __builtin_amdgcn_s_barrier();

        const char* AsB = (const char*)&As[cur][0];
        const char* BsB = (const char*)&Bs[cur][0];
        #pragma unroll
        for (int ks = 0; ks < 2; ks++) {
            bf16x8 af[4], bfr[4];
            #pragma unroll
            for (int mi = 0; mi < 4; mi++) {
                int r = wr * 64 + mi * 16 + li;
                u32 off = ((u32)(r * 128 + (ks * 32 + lk * 8) * 2)) ^ (((u32)(r & 7)) << 4);
                af[mi] = *reinterpret_cast<const bf16x8*>(AsB + off);
            }
            #pragma unroll
            for (int ni = 0; ni < 4; ni++) {
                int r = wc * 64 + ni * 16 + li;
                u32 off = ((u32)(r * 128 + (ks * 32 + lk * 8) * 2)) ^ (((u32)(r & 7)) << 4);
                bfr[ni] = *reinterpret_cast<const bf16x8*>(BsB + off);
            }
            #pragma unroll
            for (int mi = 0; mi < 4; mi++)
                #pragma unroll
                for (int ni = 0; ni < 4; ni++)
                    acc[mi][ni] = mfma16(af[mi], bfr[ni], acc[mi][ni]);
        }
        asm volatile("s_waitcnt lgkmcnt(0)" ::: "memory");
        __builtin_amdgcn_s_barrier();
    }
    #pragma unroll
    for (int mi = 0; mi < 4; mi++) {
        #pragma unroll
        for (int ni = 0; ni < 4; ni++) {
            #pragma unroll
            for (int r = 0; r < 4; r++) {
                int m = m0 + wr * 64 + mi * 16 + lk * 4 + r;
                int n = n0 + wc * 64 + ni * 16 + li;
                int oc = AFF_ROW ? m : n;
                float v = acc[mi][ni][r];
                if (bias) v += bias[b * biasBS + oc];
                float y = v * gamma[oc] + beta[oc];
                y = fmaxf(y, 0.f);
                if constexpr (sizeof(OT) == 2) Cb[(size_t)m * ldc + n] = f2bf(y);
                else                           Cb[(size_t)m * ldc + n] = y;
            }
        }
    }
}

// ---------------- fused 3-op gemm: z = op*4 + b; op0=q1, op1=k1, op2=v ----------------
__global__ __launch_bounds__(256) void k_gemm_tri(
    const u16* __restrict__ xT, long xBS,
    const u16* __restrict__ Wq, const u16* __restrict__ Wk, const u16* __restrict__ Wv,
    u16* __restrict__ Cq, u16* __restrict__ Ck2, u16* __restrict__ Cv, long cBS,
    const float* __restrict__ pg, const float* __restrict__ ckb, const float* __restrict__ cvb) {
    __shared__ u16 As[2][128 * 64];
    __shared__ u16 Bs[2][128 * 64];
    int z = blockIdx.z;
    int op = z >> 2, b = z & 3;
    const u16* Ab; const u16* Bb; u16* Cb; int ldc;
    const float* gamma; const float* beta; const float* bias;
    int m0, n0;
    if (op == 2) {
        Ab = Wv; Bb = xT + (size_t)b * xBS; Cb = Cv + (size_t)b * cBS; ldc = 4096;
        gamma = pg + 2048; beta = pg + 2304; bias = cvb;
        m0 = blockIdx.y * 128; n0 = blockIdx.x * 128;
    } else if (op == 1) {
        Ab = xT + (size_t)b * xBS; Bb = Wk; Cb = Ck2 + (size_t)b * cBS; ldc = 256;
        gamma = pg + 1024; beta = pg + 1280; bias = ckb;
        m0 = blockIdx.x * 128; n0 = blockIdx.y * 128;
    } else {
        Ab = xT + (size_t)b * xBS; Bb = Wq; Cb = Cq + (size_t)b * cBS; ldc = 256;
        gamma = pg + 0; beta = pg + 256; bias = nullptr;
        m0 = blockIdx.x * 128; n0 = blockIdx.y * 128;
    }
    int t = threadIdx.x;
    int lane = t & 63, wid = t >> 6;
    int wr = wid >> 1, wc = wid & 1;
    int li = lane & 15, lk = lane >> 4;

    f32x4 acc[4][4] = {};

    auto stage = [&](int k0, int buf) {
        #pragma unroll
        for (int j = 0; j < 4; j++) {
            int c = wid * 4 + j;
            u32 pl = (u32)c * 1024 + (u32)lane * 16;
            u32 r = pl >> 7;
            u32 q = (pl & 127) ^ ((r & 7) << 4);
            gll16(Ab + (size_t)(m0 + r) * 512 + k0 + (q >> 1), &As[buf][0] + (c << 9));
            gll16(Bb + (size_t)(n0 + r) * 512 + k0 + (q >> 1), &Bs[buf][0] + (c << 9));
        }
    };

    stage(0, 0);

    for (int kst = 0; kst < 8; kst++) {
        int cur = kst & 1;
        if (kst + 1 < 8) {
            stage((kst + 1) << 6, cur ^ 1);
            asm volatile("s_waitcnt vmcnt(8)" ::: "memory");
        } else {
            asm volatile("s_waitcnt vmcnt(0)" ::: "memory");
        }
        __builtin_amdgcn_sched_barrier(0);
        __builtin_amdgcn_s_barrier();

        const char* AsB = (const char*)&As[cur][0];
        const char* BsB = (const char*)&Bs[cur][0];
        #pragma unroll
        for (int ks = 0; ks < 2; ks++) {
            bf16x8 af[4], bfr[4];
            #pragma unroll
            for (int mi = 0; mi < 4; mi++) {
                int r = wr * 64 + mi * 16 + li;
                u32 off = ((u32)(r * 128 + (ks * 32 + lk * 8) * 2)) ^ (((u32)(r & 7)) << 4);
                af[mi] = *reinterpret_cast<const bf16x8*>(AsB + off);
            }
            #pragma unroll
            for (int ni = 0; ni < 4; ni++) {
                int r = wc * 64 + ni * 16 + li;
                u32 off = ((u32)(r * 128 + (ks * 32 + lk * 8) * 2)) ^ (((u32)(r & 7)) << 4);
                bfr[ni] = *reinterpret_cast<const bf16x8*>(BsB + off);
            }
            #pragma unroll
            for (int mi = 0; mi < 4; mi++)
                #pragma unroll
                for (int ni = 0; ni < 4; ni++)
                    acc[mi][ni] = mfma16(af[mi], bfr[ni], acc[mi][ni]);
        }
        asm volatile("s_waitcnt lgkmcnt(0)" ::: "memory");
        __builtin_amdgcn_s_barrier();
    }
    #pragma unroll
    for (int mi = 0; mi < 4; mi++) {
        #pragma unroll
        for (int ni = 0; ni < 4; ni++) {
            #pragma unroll
            for (int r = 0; r < 4; r++) {
                int m = m0 + wr * 64 + mi * 16 + lk * 4 + r;
                int n = n0 + wc * 64 + ni * 16 + li;
                int oc = (op == 2) ? m : n;
                float v = acc[mi][ni][r];
                if (bias) v += bias[b * 256 + oc];
                float y = v * gamma[oc] + beta[oc];
                y = fmaxf(y, 0.f);
                Cb[(size_t)m * ldc + n] = f2bf(y);
            }
        }
    }
}

// ---------------- fused pair gemm (q2+k2): blockIdx.z = op*4 + b ----------------
__global__ __launch_bounds__(256) void k_gemm_pair(
    const u16* __restrict__ A0, const u16* __restrict__ A1, long aBS, int lda,
    const u16* __restrict__ B0, const u16* __restrict__ B1, int ldb,
    u16* __restrict__ C0, u16* __restrict__ C1, long cBS, int ldc,
    const float* __restrict__ g0, const float* __restrict__ be0,
    const float* __restrict__ g1, const float* __restrict__ be1, int K) {
    __shared__ u16 As[2][128 * 64];
    __shared__ u16 Bs[2][128 * 64];
    int z = blockIdx.z;
    int op = z >> 2, b = z & 3;
    const u16* Ab = (op ? A1 : A0) + (size_t)b * aBS;
    const u16* Bb = op ? B1 : B0;
    u16* Cb = (op ? C1 : C0) + (size_t)b * cBS;
    const float* gamma = op ? g1 : g0;
    const float* beta  = op ? be1 : be0;
    int m0 = blockIdx.x * 128, n0 = blockIdx.y * 128;
    int t = threadIdx.x;
    int lane = t & 63, wid = t >> 6;
    int wr = wid >> 1, wc = wid & 1;
    int li = lane & 15, lk = lane >> 4;

    f32x4 acc[4][4] = {};

    auto stage = [&](int k0, int buf) {
        #pragma unroll
        for (int j = 0; j < 4; j++) {
            int c = wid * 4 + j;
            u32 pl = (u32)c * 1024 + (u32)lane * 16;
            u32 r = pl >> 7;
            u32 q = (pl & 127) ^ ((r & 7) << 4);
            gll16(Ab + (size_t)(m0 + r) * lda + k0 + (q >> 1), &As[buf][0] + (c << 9));
            gll16(Bb + (size_t)(n0 + r) * ldb + k0 + (q >> 1), &Bs[buf][0] + (c << 9));
        }
    };

    const int nk = K >> 6;
    stage(0, 0);

    for (int kst = 0; kst < nk; kst++) {
        int cur = kst & 1;
        if (kst + 1 < nk) {
            stage((kst + 1) << 6, cur ^ 1);
            asm volatile("s_waitcnt vmcnt(8)" ::: "memory");
        } else {
            asm volatile("s_waitcnt vmcnt(0)" ::: "memory");
        }
        __builtin_amdgcn_sched_barrier(0);
        __builtin_amdgcn_s_barrier();

        const char* AsB = (const char*)&As[cur][0];
        const char* BsB = (const char*)&Bs[cur][0];
        #pragma unroll
        for (int ks = 0; ks < 2; ks++) {
            bf16x8 af[4], bfr[4];
            #pragma unroll
            for (int mi = 0; mi < 4; mi++) {
                int r = wr * 64 + mi * 16 + li;
                u32 off = ((u32)(r * 128 + (ks * 32 + lk * 8) * 2)) ^ (((u32)(r & 7)) << 4);
                af[mi] = *reinterpret_cast<const bf16x8*>(AsB + off);
            }
            #pragma unroll
            for (int ni = 0; ni < 4; ni++) {
                int r = wc * 64 + ni * 16 + li;
                u32 off = ((u32)(r * 128 + (ks * 32 + lk * 8) * 2)) ^ (((u32)(r & 7)) << 4);
                bfr[ni] = *reinterpret_cast<const bf16x8*>(BsB + off);
            }
            #pragma unroll
            for (int mi = 0; mi < 4; mi++)
                #pragma unroll
                for (int ni = 0; ni < 4; ni++)
                    acc[mi][ni] = mfma16(af[mi], bfr[ni], acc[mi][ni]);
        }
        asm volatile("s_waitcnt lgkmcnt(0)" ::: "memory");
        __builtin_amdgcn_s_barrier();
    }
    #pragma unroll
    for (int mi = 0; mi < 4; mi++) {
        #pragma unroll
        for (int ni = 0; ni < 4; ni++) {
            #pragma unroll
            for (int r = 0; r < 4; r++) {
                int m = m0 + wr * 64 + mi * 16 + lk * 4 + r;
                int n = n0 + wc * 64 + ni * 16 + li;
                float v = acc[mi][ni][r];
                float y = v * gamma[n] + beta[n];
                y = fmaxf(y, 0.f);
                Cb[(size_t)m * ldc + n] = f2bf(y);
            }
        }
    }
}

// ---------------- flash attention v8: P stays in registers (k-slot permutation) ----------------
// k-slot s=lk*8+j maps to key κ(s) = (j>>2)*16 + lk*4 + (j&3): lane's own S^T values ARE its PV B-frag.
// V A-frag reads κ-ordered keys: two ds_read_b64 per ct (bytes lk*8 and 32+lk*8, 16B-granular swizzle).
__global__ __launch_bounds__(256, 2) void k_attn(const u16* __restrict__ Q, const u16* __restrict__ Kt,
                                                 const u16* __restrict__ V, u16* __restrict__ Op,
                                                 float2* __restrict__ ML) {
    __shared__ u16 Ks[2][32 * 256];
    __shared__ u16 Vs[2][256 * 32];
    int wg = blockIdx.x;
    int bs = wg & 15, qt = wg >> 4;
    int b = bs >> 2, sp = bs & 3;
    int n0 = qt * 128;
    int k0 = sp * 1024;
    const size_t S = (size_t)4096 * 256;
    const u16* Qb = Q + (size_t)b * S + (size_t)n0 * 256;
    const u16* Kb = Kt + (size_t)b * S + (size_t)k0 * 256;
    const u16* Vb = V + (size_t)b * S + k0;      // channel-major [256][4096]
    int t = threadIdx.x;
    int lane = t & 63, wid = t >> 6;
    int li = lane & 15, lk = lane >> 4;
    int qw = wid * 32;

    bf16x8 qf[2][8];
    #pragma unroll
    for (int fq = 0; fq < 2; fq++)
        #pragma unroll
        for (int kc = 0; kc < 8; kc++)
            qf[fq][kc] = *reinterpret_cast<const bf16x8*>(Qb + (size_t)(qw + fq * 16 + li) * 256 + kc * 32 + lk * 8);

    f32x4 acc[2][16] = {};
    float M[2] = {-1e30f, -1e30f};
    float L[2] = {0.f, 0.f};
    const float SCL = 0.0625f * 1.44269504088896f;

    auto stage = [&](int kt, int buf) {
        const u16* Kp = Kb + (size_t)kt * 32 * 256;
        const u16* Vp = Vb + kt * 32;
        u16* Kd = &Ks[buf][0];
        u16* Vd = &Vs[buf][0];
        #pragma unroll
        for (int j = 0; j < 4; j++) {
            int c = wid * 4 + j;
            u32 pl = (u32)c * 1024 + (u32)lane * 16;
            u32 krow = pl >> 9;
            u32 kq = (pl & 511) ^ ((krow & 7) << 4);
            gll16(Kp + krow * 256 + (kq >> 1), Kd + (c << 9));
            u32 vcc = pl >> 6;
            u32 vq = (pl & 63) ^ (((vcc >> 1) & 3) << 4);
            gll16(Vp + (size_t)vcc * 4096 + (vq >> 1), Vd + (c << 9));
        }
    };

    stage(0, 0);

    for (int kt = 0; kt < 32; kt++) {
        int cur = kt & 1;
        if (kt + 1 < 32) {
            stage(kt + 1, cur ^ 1);
            asm volatile("s_waitcnt vmcnt(8)" ::: "memory");
        } else {
            asm volatile("s_waitcnt vmcnt(0)" ::: "memory");
        }
        __builtin_amdgcn_sched_barrier(0);
        __builtin_amdgcn_s_barrier();

        const char* KsB = (const char*)&Ks[cur][0];
        const char* VsB = (const char*)&Vs[cur][0];

        // S^T = K · Q
        __builtin_amdgcn_s_setprio(1);
        f32x4 sf[2][2] = {};
        #pragma unroll
        for (int mk = 0; mk < 2; mk++) {
            #pragma unroll
            for (int kc = 0; kc < 8; kc++) {
                int row = mk * 16 + li;
                u32 off = (u32)(row * 512) + (((u32)(kc * 64 + lk * 16)) ^ (((u32)(row & 7)) << 4));
                bf16x8 kb = *reinterpret_cast<const bf16x8*>(KsB + off);
                sf[mk][0] = mfma16(kb, qf[0][kc], sf[mk][0]);
                sf[mk][1] = mfma16(kb, qf[1][kc], sf[mk][1]);
            }
        }
        __builtin_amdgcn_s_setprio(0);

        // lane-local max guard
        float lm[2];
        #pragma unroll
        for (int fq = 0; fq < 2; fq++) {
            lm[fq] = fmaxf(fmaxf(fmaxf(sf[0][fq][0], sf[0][fq][1]), fmaxf(sf[0][fq][2], sf[0][fq][3])),
                           fmaxf(fmaxf(sf[1][fq][0], sf[1][fq][1]), fmaxf(sf[1][fq][2], sf[1][fq][3]))) * SCL;
        }
        bool ok = (lm[0] <= M[0] + 24.f) && (lm[1] <= M[1] + 24.f);
        if (!__all(ok ? 1 : 0)) {
            #pragma unroll
            for (int fq = 0; fq < 2; fq++) {
                float mx = lm[fq];
                mx = fmaxf(mx, __shfl_xor(mx, 16));
                mx = fmaxf(mx, __shfl_xor(mx, 32));
                float nM = fmaxf(M[fq], mx);
                float rs = exp2f(M[fq] - nM);
                L[fq] *= rs; M[fq] = nM;
                #pragma unroll
                for (int ct = 0; ct < 16; ct++) {
                    acc[fq][ct][0] *= rs; acc[fq][ct][1] *= rs;
                    acc[fq][ct][2] *= rs; acc[fq][ct][3] *= rs;
                }
            }
        }

        // P in registers: exp2 + pack into the PV B-fragment directly (no LDS)
        bf16x8 pb[2];
        #pragma unroll
        for (int fq = 0; fq < 2; fq++) {
            float p00 = exp2f(sf[0][fq][0] * SCL - M[fq]);
            float p01 = exp2f(sf[0][fq][1] * SCL - M[fq]);
            float p02 = exp2f(sf[0][fq][2] * SCL - M[fq]);
            float p03 = exp2f(sf[0][fq][3] * SCL - M[fq]);
            float p10 = exp2f(sf[1][fq][0] * SCL - M[fq]);
            float p11 = exp2f(sf[1][fq][1] * SCL - M[fq]);
            float p12 = exp2f(sf[1][fq][2] * SCL - M[fq]);
            float p13 = exp2f(sf[1][fq][3] * SCL - M[fq]);
            L[fq] += ((p00 + p01) + (p02 + p03)) + ((p10 + p11) + (p12 + p13));
            BF8 pw;
            pw.u.x = cvtpk(p00, p01);
            pw.u.y = cvtpk(p02, p03);
            pw.u.z = cvtpk(p10, p11);
            pw.u.w = cvtpk(p12, p13);
            pb[fq] = pw.v;
        }

        // O^T += V^T · P^T (V read in κ-order: 2 x b64 per ct)
        __builtin_amdgcn_s_setprio(1);
        #pragma unroll
        for (int ct = 0; ct < 16; ct++) {
            int vr = ct * 16 + li;
            u32 sw = ((u32)((vr >> 1) & 3)) << 4;
            u32 lo = (u32)(vr * 64) + (((u32)(lk * 8)) ^ sw);
            u32 hi = (u32)(vr * 64) + (((u32)(32 + lk * 8)) ^ sw);
            BF8 va;
            *reinterpret_cast<uint2*>(&va.u.x) = *reinterpret_cast<const uint2*>(VsB + lo);
            *reinterpret_cast<uint2*>(&va.u.z) = *reinterpret_cast<const uint2*>(VsB + hi);
            acc[0][ct] = mfma16(va.v, pb[0], acc[0][ct]);
            acc[1][ct] = mfma16(va.v, pb[1], acc[1][ct]);
        }
        __builtin_amdgcn_s_setprio(0);
        asm volatile("s_waitcnt lgkmcnt(0)" ::: "memory");
        __builtin_amdgcn_s_barrier();
    }

    #pragma unroll
    for (int fq = 0; fq < 2; fq++) {
        L[fq] += __shfl_xor(L[fq], 16);
        L[fq] += __shfl_xor(L[fq], 32);
    }

    size_t obase = (size_t)(sp * 4 + b) * 4096 + n0;
    #pragma unroll
    for (int fq = 0; fq < 2; fq++) {
        int q = qw + fq * 16 + li;
        #pragma unroll
        for (int ct = 0; ct < 16; ct++) {
            uint2 ow;
            ow.x = cvtpk(acc[fq][ct][0], acc[fq][ct][1]);
            ow.y = cvtpk(acc[fq][ct][2], acc[fq][ct][3]);
            *reinterpret_cast<uint2*>(&Op[(obase + q) * 256 + ct * 16 + lk * 4]) = ow;
        }
    }
    if (lk == 0) {
        #pragma unroll
        for (int fq = 0; fq < 2; fq++) {
            float2 v; v.x = M[fq]; v.y = L[fq];
            ML[obase + qw + fq * 16 + li] = v;
        }
    }
}

// ---------------- merge split-KV partials -> ctx bf16 (vectorized: 4 q/block, 4 ch/thread) --------
__global__ __launch_bounds__(256) void k_merge(const u16* __restrict__ Op, const float2* __restrict__ ML,
                                               u16* __restrict__ ctx) {
    int wg = blockIdx.x;               // 4096 = 4b x 1024 q-groups
    int t = threadIdx.x;
    int b = wg >> 10;
    int q = (wg & 1023) * 4 + (t >> 6);
    int c4 = (t & 63) * 4;
    float2 ml[4];
    float Mx = -1e30f;
    #pragma unroll
    for (int s = 0; s < 4; s++) { ml[s] = ML[((size_t)(s * 4 + b) << 12) + q]; Mx = fmaxf(Mx, ml[s].x); }
    float Lt = 0.f, w[4];
    #pragma unroll
    for (int s = 0; s < 4; s++) { w[s] = exp2f(ml[s].x - Mx); Lt += ml[s].y * w[s]; }
    float inv = 1.f / Lt;
    float o0 = 0.f, o1 = 0.f, o2 = 0.f, o3 = 0.f;
    #pragma unroll
    for (int s = 0; s < 4; s++) {
        uint2 v = *reinterpret_cast<const uint2*>(&Op[(((size_t)(s * 4 + b) << 12) + q) * 256 + c4]);
        o0 += w[s] * bf2f((u16)(v.x & 0xFFFFu));
        o1 += w[s] * bf2f((u16)(v.x >> 16));
        o2 += w[s] * bf2f((u16)(v.y & 0xFFFFu));
        o3 += w[s] * bf2f((u16)(v.y >> 16));
    }
    uint2 ow;
    ow.x = cvtpk(o0 * inv, o1 * inv);
    ow.y = cvtpk(o2 * inv, o3 * inv);
    *reinterpret_cast<uint2*>(&ctx[(((size_t)b << 12) + q) * 256 + c4]) = ow;
}

extern "C" void kernel_launch(void* const* d_in, const int* in_sizes, int n_in,
                              void* d_out, int out_size, void* d_ws, size_t ws_size,
                              hipStream_t stream) {
    const void* x   = d_in[0];
    const void* qW1 = d_in[1];  const void* qg1 = d_in[2];  const void* qb1 = d_in[3];
    const void* qW2 = d_in[4];  const void* qg2 = d_in[5];  const void* qb2 = d_in[6];
    const void* kW1 = d_in[7];  const void* kg1 = d_in[8];  const void* kb1 = d_in[9];
    const void* kW2 = d_in[10]; const void* kg2 = d_in[11]; const void* kb2 = d_in[12];
    const void* vW  = d_in[13]; const void* vg  = d_in[14]; const void* vb  = d_in[15];
    const void* oW  = d_in[16]; const void* og  = d_in[17]; const void* ob  = d_in[18];

    char* ws = (char*)d_ws;
    int*   dflag = (int*)ws;
    float* xg = (float*)(ws + 4096);
    float* ck = (float*)(ws + 16384);
    float* cv = (float*)(ws + 20480);
    float* pg = (float*)(ws + 24576);
    u16* wb = (u16*)(ws + 40960);
    u16* qW1b = wb;
    u16* qW2b = wb + 131072;
    u16* kW1b = wb + 196608;
    u16* kW2b = wb + 327680;
    u16* vWb  = wb + 393216;
    u16* oWb  = wb + 524288;
    float* partials = (float*)(ws + 0x180000); // 512KB
    float2* mlBuf = (float2*)(ws + 0x200000);  // 512KB
    const size_t S = (size_t)4096 * 256;
    const size_t SLOT = 4 * S;
    u16* s0 = (u16*)(ws + 0x280000);
    u16* s1 = s0 + SLOT;
    u16* s2 = s1 + SLOT;
    u16* s3 = s2 + SLOT;
    u16* xT = (u16*)d_out;
    u16* k1buf = (u16*)d_out + 8388608;
    u16* opart = (u16*)d_out;
    u16* ctxBuf = s1;

    k_detect<<<1, 256, 0, stream>>>((const u32*)x, dflag);
    k_xpose<<<dim3(64, 8, 4), 256, 0, stream>>>(x, dflag, xT, partials);
    k_mean2<<<8, 256, 0, stream>>>(partials, xg);
    k_consts<<<1024, 64, 0, stream>>>(kW1, vW, dflag, xg, ck, cv);
    k_wconv<<<2560, 256, 0, stream>>>(qW1, qW2, kW1, kW2, vW, oW, dflag, wb);
    k_pconv<<<14, 256, 0, stream>>>(qg1, qb1, qg2, qb2, kg1, kb1, kg2, kb2,
                                    vg, vb, og, ob, dflag, pg);

    const long XS = (long)4096 * 512;
    // fused q1 + k1 + v
    k_gemm_tri<<<dim3(32, 2, 12), 256, 0, stream>>>(xT, XS, qW1b, kW1b, vWb,
        s0, k1buf, s3, (long)S, pg, ck, cv);
    // fused q2 + k2
    k_gemm_pair<<<dim3(32, 2, 8), 256, 0, stream>>>(s0, k1buf, (long)S, 256,
        qW2b, kW2b, 256, s1, s2, (long)S, 256,
        pg + 512, pg + 768, pg + 1536, pg + 1792, 256);
    // attention (split-KV x4): Q(s1), K(s2), V(s3) -> partials in d_out, ML
    k_attn<<<512, 256, 0, stream>>>(s1, s2, s3, opart, mlBuf);
    // merge -> ctx (s1)
    k_merge<<<4096, 256, 0, stream>>>(opart, mlBuf, ctxBuf);
    // out projection -> d_out as f32 [B][512][4096]
    k_gemm_bt<true, float><<<dim3(4, 32, 4), 256, 0, stream>>>(oWb, 0, 256, ctxBuf, (long)S, 256,
        (float*)d_out, (long)512 * 4096, 4096, pg + 2560, pg + 3072, nullptr, 0, 256);
}

// Round 17
// 198.175 us; speedup vs baseline: 2.2614x; 1.0100x over previous
//
#include <hip/hip_runtime.h>
#include <stdint.h>

typedef __bf16 bf16x8 __attribute__((ext_vector_type(8)));
typedef float f32x4 __attribute__((ext_vector_type(4)));
typedef unsigned short u16;
typedef uint32_t u32;

union V16 { uint4 v; u16 e[8]; };
union BF8 { uint4 u; bf16x8 v; };

__device__ __forceinline__ float bf2f(u16 h) {
    u32 u = ((u32)h) << 16; float f; __builtin_memcpy(&f, &u, 4); return f;
}
__device__ __forceinline__ u16 f2bf(float f) {
    u32 u; __builtin_memcpy(&u, &f, 4);
    u32 r = (u + 0x7FFFu + ((u >> 16) & 1u)) >> 16; return (u16)r;
}
__device__ __forceinline__ u32 cvtpk(float lo, float hi) {
    u32 r;
    asm("v_cvt_pk_bf16_f32 %0, %1, %2" : "=v"(r) : "v"(lo), "v"(hi));
    return r;
}
__device__ __forceinline__ f32x4 mfma16(bf16x8 a, bf16x8 b, f32x4 c) {
    return __builtin_amdgcn_mfma_f32_16x16x32_bf16(a, b, c, 0, 0, 0);
}
// async 16B global -> LDS (wave-uniform LDS base; HW adds lane*16)
__device__ __forceinline__ void gll16(const u16* g, u16* l) {
    __builtin_amdgcn_global_load_lds(
        (const __attribute__((address_space(1))) unsigned int*)g,
        (__attribute__((address_space(3))) unsigned int*)l, 16, 0, 0);
}
// flag: 0=bf16, 1=f32, 2=f64
__device__ __forceinline__ float loadElem(const void* p, size_t i, int fl) {
    if (fl == 1) return ((const float*)p)[i];
    if (fl == 2) return (float)((const double*)p)[i];
    return bf2f(((const u16*)p)[i]);
}

// ---------------- dtype detect on x ----------------
__global__ __launch_bounds__(256) void k_detect(const u32* __restrict__ xw, int* __restrict__ flag) {
    int t = threadIdx.x;
    int cA = 0, cB = 0;
    #pragma unroll
    for (int i = 0; i < 16; i++) {
        u32 w = xw[i * 256 + t];
        cA += (((w >> 23) & 0xFFu) >= 0xC0u) ? 1 : 0;
        cB += (((w >> 7)  & 0xFFu) >= 0xC0u) ? 1 : 0;
    }
    #pragma unroll
    for (int m = 32; m >= 1; m >>= 1) { cA += __shfl_xor(cA, m); cB += __shfl_xor(cB, m); }
    __shared__ int sA[4], sB[4];
    if ((t & 63) == 0) { sA[t >> 6] = cA; sB[t >> 6] = cB; }
    __syncthreads();
    if (t == 0) {
        int a = sA[0] + sA[1] + sA[2] + sA[3];
        int b = sB[0] + sB[1] + sB[2] + sB[3];
        *flag = (a > 64) ? 2 : ((b > 64) ? 1 : 0);
    }
}

// ---------------- transpose(+cast) x -> xT bf16, with per-block mean partials ----------------
__global__ __launch_bounds__(256) void k_xpose(const void* __restrict__ xv, const int* __restrict__ dt,
                                               u16* __restrict__ xT, float* __restrict__ partial) {
    __shared__ u16 tile[64][72];
    int b = blockIdx.z;
    int n0 = blockIdx.x * 64, c0 = blockIdx.y * 64;
    u16* xTb = xT + (size_t)b * 4096 * 512;
    int t = threadIdx.x;
    int fl = *dt;
    const size_t xbase = (size_t)b * 512 * 4096;
    if (fl == 1) {
        const float* xb = (const float*)xv + xbase;
        int cr = t >> 4, n4 = (t & 15) * 4;
        #pragma unroll
        for (int i = 0; i < 4; i++) {
            int c = cr + i * 16;
            float4 v = *reinterpret_cast<const float4*>(xb + (size_t)(c0 + c) * 4096 + n0 + n4);
            tile[n4 + 0][c] = f2bf(v.x); tile[n4 + 1][c] = f2bf(v.y);
            tile[n4 + 2][c] = f2bf(v.z); tile[n4 + 3][c] = f2bf(v.w);
            float s = (v.x + v.y) + (v.z + v.w);
            s += __shfl_xor(s, 1); s += __shfl_xor(s, 2);
            s += __shfl_xor(s, 4); s += __shfl_xor(s, 8);
            if ((t & 15) == 0)
                partial[((size_t)b * 512 + c0 + c) * 64 + blockIdx.x] = s;
        }
    } else {
        int c4 = t >> 6, n = t & 63;
        for (int i = 0; i < 16; i++) {
            int c = c4 + i * 4;
            float v = loadElem(xv, xbase + (size_t)(c0 + c) * 4096 + n0 + n, fl);
            tile[n][c] = f2bf(v);
            float s = v;
            #pragma unroll
            for (int m = 32; m >= 1; m >>= 1) s += __shfl_xor(s, m);
            if (n == 0)
                partial[((size_t)b * 512 + c0 + c) * 64 + blockIdx.x] = s;
        }
    }
    __syncthreads();
    int nr = t >> 3, c8 = (t & 7) * 8;
    #pragma unroll
    for (int i = 0; i < 2; i++) {
        int n = nr + i * 32;
        V16 v;
        #pragma unroll
        for (int j = 0; j < 8; j++) v.e[j] = tile[n][c8 + j];
        *reinterpret_cast<uint4*>(xTb + (size_t)(n0 + n) * 512 + c0 + c8) = v.v;
    }
}

// ---------------- reduce partials -> xg mean (deterministic) ----------------
__global__ __launch_bounds__(256) void k_mean2(const float* __restrict__ partial, float* __restrict__ xg) {
    int bc = blockIdx.x * 256 + threadIdx.x;
    const float* p = partial + (size_t)bc * 64;
    float s = 0.f;
    #pragma unroll
    for (int i = 0; i < 64; i++) s += p[i];
    xg[bc] = s * (1.f / 4096.f);
}

// ---------------- fold mean through kW1/vW cols [0,512): per-(b,o) f32 bias ----------------
__global__ __launch_bounds__(64) void k_consts(const void* __restrict__ kW1, const void* __restrict__ vW,
                                               const int* __restrict__ dt, const float* __restrict__ xg,
                                               float* __restrict__ ck, float* __restrict__ cv) {
    int bo = blockIdx.x; int b = bo >> 8; int o = bo & 255;
    int l = threadIdx.x;
    int fl = *dt;
    const float* g = xg + b * 512;
    float sk = 0.f, sv = 0.f;
    for (int c = l; c < 512; c += 64) {
        float xv = g[c];
        sk += loadElem(kW1, (size_t)o * 1024 + c, fl) * xv;
        sv += loadElem(vW,  (size_t)o * 1024 + c, fl) * xv;
    }
    #pragma unroll
    for (int m = 32; m >= 1; m >>= 1) { sk += __shfl_xor(sk, m); sv += __shfl_xor(sv, m); }
    if (l == 0) { ck[bo] = sk; cv[bo] = sv; }
}

// ---------------- weights -> bf16 + affine params -> f32 (fused) ----------------
__global__ __launch_bounds__(256) void k_wpconv(const void* __restrict__ qW1, const void* __restrict__ qW2,
                                                const void* __restrict__ kW1, const void* __restrict__ kW2,
                                                const void* __restrict__ vW, const void* __restrict__ oW,
                                                const void* qg1, const void* qb1, const void* qg2, const void* qb2,
                                                const void* kg1, const void* kb1, const void* kg2, const void* kb2,
                                                const void* vg, const void* vb, const void* og, const void* ob,
                                                const int* __restrict__ dt, u16* __restrict__ dst,
                                                float* __restrict__ pg) {
    int blk = blockIdx.x;
    int fl = *dt;
    if (blk < 2560) {
        int i = blk * 256 + threadIdx.x;
        const void* s; size_t so;
        if (i < 131072)      { s = qW1; so = (size_t)i; }
        else if (i < 196608) { int j = i - 131072; s = qW2; so = (size_t)j; }
        else if (i < 327680) { int j = i - 196608; s = kW1; so = (size_t)(j >> 9) * 1024 + 512 + (j & 511); }
        else if (i < 393216) { int j = i - 327680; s = kW2; so = (size_t)j; }
        else if (i < 524288) { int j = i - 393216; s = vW;  so = (size_t)(j >> 9) * 1024 + 512 + (j & 511); }
        else                 { int j = i - 524288; s = oW;  so = (size_t)j; }
        dst[i] = f2bf(loadElem(s, so, fl));
    } else {
        int j = (blk - 2560) * 256 + threadIdx.x;
        if (j >= 3584) return;
        const void* s; int o;
        if (j < 256)       { s = qg1; o = j; }
        else if (j < 512)  { s = qb1; o = j - 256; }
        else if (j < 768)  { s = qg2; o = j - 512; }
        else if (j < 1024) { s = qb2; o = j - 768; }
        else if (j < 1280) { s = kg1; o = j - 1024; }
        else if (j < 1536) { s = kb1; o = j - 1280; }
        else if (j < 1792) { s = kg2; o = j - 1536; }
        else if (j < 2048) { s = kb2; o = j - 1792; }
        else if (j < 2304) { s = vg;  o = j - 2048; }
        else if (j < 2560) { s = vb;  o = j - 2304; }
        else if (j < 3072) { s = og;  o = j - 2560; }
        else               { s = ob;  o = j - 3072; }
        pg[j] = loadElem(s, (size_t)o, fl);
    }
}

// ---------------- gemm_bt v2 (out-proj): async dbuf via global_load_lds ----------------
template<bool AFF_ROW, typename OT>
__global__ __launch_bounds__(256) void k_gemm_bt(
    const u16* __restrict__ A, long aBS, int lda,
    const u16* __restrict__ Bm, long bBS, int ldb,
    OT* __restrict__ C, long cBS, int ldc,
    const float* __restrict__ gamma, const float* __restrict__ beta,
    const float* __restrict__ bias, int biasBS, int K) {
    __shared__ u16 As[2][128 * 64];
    __shared__ u16 Bs[2][128 * 64];
    int b = blockIdx.z;
    const u16* Ab = A + (size_t)b * aBS;
    const u16* Bb = Bm + (size_t)b * bBS;
    OT* Cb = C + (size_t)b * cBS;
    int m0 = blockIdx.x * 128, n0 = blockIdx.y * 128;
    int t = threadIdx.x;
    int lane = t & 63, wid = t >> 6;
    int wr = wid >> 1, wc = wid & 1;
    int li = lane & 15, lk = lane >> 4;

    f32x4 acc[4][4] = {};

    auto stage = [&](int k0, int buf) {
        #pragma unroll
        for (int j = 0; j < 4; j++) {
            int c = wid * 4 + j;
            u32 pl = (u32)c * 1024 + (u32)lane * 16;
            u32 r = pl >> 7;
            u32 q = (pl & 127) ^ ((r & 7) << 4);
            gll16(Ab + (size_t)(m0 + r) * lda + k0 + (q >> 1), &As[buf][0] + (c << 9));
            gll16(Bb + (size_t)(n0 + r) * ldb + k0 + (q >> 1), &Bs[buf][0] + (c << 9));
        }
    };

    const int nk = K >> 6;
    stage(0, 0);

    for (int kst = 0; kst < nk; kst++) {
        int cur = kst & 1;
        if (kst + 1 < nk) {
            stage((kst + 1) << 6, cur ^ 1);
            asm volatile("s_waitcnt vmcnt(8)" ::: "memory");
        } else {
            asm volatile("s_waitcnt vmcnt(0)" ::: "memory");
        }
        __builtin_amdgcn_sched_barrier(0);
        __builtin_amdgcn_s_barrier();

        const char* AsB = (const char*)&As[cur][0];
        const char* BsB = (const char*)&Bs[cur][0];
        #pragma unroll
        for (int ks = 0; ks < 2; ks++) {
            bf16x8 af[4], bfr[4];
            #pragma unroll
            for (int mi = 0; mi < 4; mi++) {
                int r = wr * 64 + mi * 16 + li;
                u32 off = ((u32)(r * 128 + (ks * 32 + lk * 8) * 2)) ^ (((u32)(r & 7)) << 4);
                af[mi] = *reinterpret_cast<const bf16x8*>(AsB + off);
            }
            #pragma unroll
            for (int ni = 0; ni < 4; ni++) {
                int r = wc * 64 + ni * 16 + li;
                u32 off = ((u32)(r * 128 + (ks * 32 + lk * 8) * 2)) ^ (((u32)(r & 7)) << 4);
                bfr[ni] = *reinterpret_cast<const bf16x8*>(BsB + off);
            }
            #pragma unroll
            for (int mi = 0; mi < 4; mi++)
                #pragma unroll
                for (int ni = 0; ni < 4; ni++)
                    acc[mi][ni] = mfma16(af[mi], bfr[ni], acc[mi][ni]);
        }
        asm volatile("s_waitcnt lgkmcnt(0)" ::: "memory");
        __builtin_amdgcn_s_barrier();
    }
    #pragma unroll
    for (int mi = 0; mi < 4; mi++) {
        #pragma unroll
        for (int ni = 0; ni < 4; ni++) {
            #pragma unroll
            for (int r = 0; r < 4; r++) {
                int m = m0 + wr * 64 + mi * 16 + lk * 4 + r;
                int n = n0 + wc * 64 + ni * 16 + li;
                int oc = AFF_ROW ? m : n;
                float v = acc[mi][ni][r];
                if (bias) v += bias[b * biasBS + oc];
                float y = v * gamma[oc] + beta[oc];
                y = fmaxf(y, 0.f);
                if constexpr (sizeof(OT) == 2) Cb[(size_t)m * ldc + n] = f2bf(y);
                else                           Cb[(size_t)m * ldc + n] = y;
            }
        }
    }
}

// ---------------- fused 3-op gemm: z = op*4 + b; op0=q1, op1=k1, op2=v ----------------
__global__ __launch_bounds__(256) void k_gemm_tri(
    const u16* __restrict__ xT, long xBS,
    const u16* __restrict__ Wq, const u16* __restrict__ Wk, const u16* __restrict__ Wv,
    u16* __restrict__ Cq, u16* __restrict__ Ck2, u16* __restrict__ Cv, long cBS,
    const float* __restrict__ pg, const float* __restrict__ ckb, const float* __restrict__ cvb) {
    __shared__ u16 As[2][128 * 64];
    __shared__ u16 Bs[2][128 * 64];
    int z = blockIdx.z;
    int op = z >> 2, b = z & 3;
    const u16* Ab; const u16* Bb; u16* Cb; int ldc;
    const float* gamma; const float* beta; const float* bias;
    int m0, n0;
    if (op == 2) {
        Ab = Wv; Bb = xT + (size_t)b * xBS; Cb = Cv + (size_t)b * cBS; ldc = 4096;
        gamma = pg + 2048; beta = pg + 2304; bias = cvb;
        m0 = blockIdx.y * 128; n0 = blockIdx.x * 128;
    } else if (op == 1) {
        Ab = xT + (size_t)b * xBS; Bb = Wk; Cb = Ck2 + (size_t)b * cBS; ldc = 256;
        gamma = pg + 1024; beta = pg + 1280; bias = ckb;
        m0 = blockIdx.x * 128; n0 = blockIdx.y * 128;
    } else {
        Ab = xT + (size_t)b * xBS; Bb = Wq; Cb = Cq + (size_t)b * cBS; ldc = 256;
        gamma = pg + 0; beta = pg + 256; bias = nullptr;
        m0 = blockIdx.x * 128; n0 = blockIdx.y * 128;
    }
    int t = threadIdx.x;
    int lane = t & 63, wid = t >> 6;
    int wr = wid >> 1, wc = wid & 1;
    int li = lane & 15, lk = lane >> 4;

    f32x4 acc[4][4] = {};

    auto stage = [&](int k0, int buf) {
        #pragma unroll
        for (int j = 0; j < 4; j++) {
            int c = wid * 4 + j;
            u32 pl = (u32)c * 1024 + (u32)lane * 16;
            u32 r = pl >> 7;
            u32 q = (pl & 127) ^ ((r & 7) << 4);
            gll16(Ab + (size_t)(m0 + r) * 512 + k0 + (q >> 1), &As[buf][0] + (c << 9));
            gll16(Bb + (size_t)(n0 + r) * 512 + k0 + (q >> 1), &Bs[buf][0] + (c << 9));
        }
    };

    stage(0, 0);

    for (int kst = 0; kst < 8; kst++) {
        int cur = kst & 1;
        if (kst + 1 < 8) {
            stage((kst + 1) << 6, cur ^ 1);
            asm volatile("s_waitcnt vmcnt(8)" ::: "memory");
        } else {
            asm volatile("s_waitcnt vmcnt(0)" ::: "memory");
        }
        __builtin_amdgcn_sched_barrier(0);
        __builtin_amdgcn_s_barrier();

        const char* AsB = (const char*)&As[cur][0];
        const char* BsB = (const char*)&Bs[cur][0];
        #pragma unroll
        for (int ks = 0; ks < 2; ks++) {
            bf16x8 af[4], bfr[4];
            #pragma unroll
            for (int mi = 0; mi < 4; mi++) {
                int r = wr * 64 + mi * 16 + li;
                u32 off = ((u32)(r * 128 + (ks * 32 + lk * 8) * 2)) ^ (((u32)(r & 7)) << 4);
                af[mi] = *reinterpret_cast<const bf16x8*>(AsB + off);
            }
            #pragma unroll
            for (int ni = 0; ni < 4; ni++) {
                int r = wc * 64 + ni * 16 + li;
                u32 off = ((u32)(r * 128 + (ks * 32 + lk * 8) * 2)) ^ (((u32)(r & 7)) << 4);
                bfr[ni] = *reinterpret_cast<const bf16x8*>(BsB + off);
            }
            #pragma unroll
            for (int mi = 0; mi < 4; mi++)
                #pragma unroll
                for (int ni = 0; ni < 4; ni++)
                    acc[mi][ni] = mfma16(af[mi], bfr[ni], acc[mi][ni]);
        }
        asm volatile("s_waitcnt lgkmcnt(0)" ::: "memory");
        __builtin_amdgcn_s_barrier();
    }
    #pragma unroll
    for (int mi = 0; mi < 4; mi++) {
        #pragma unroll
        for (int ni = 0; ni < 4; ni++) {
            #pragma unroll
            for (int r = 0; r < 4; r++) {
                int m = m0 + wr * 64 + mi * 16 + lk * 4 + r;
                int n = n0 + wc * 64 + ni * 16 + li;
                int oc = (op == 2) ? m : n;
                float v = acc[mi][ni][r];
                if (bias) v += bias[b * 256 + oc];
                float y = v * gamma[oc] + beta[oc];
                y = fmaxf(y, 0.f);
                Cb[(size_t)m * ldc + n] = f2bf(y);
            }
        }
    }
}

// ---------------- fused pair gemm (q2+k2): blockIdx.z = op*4 + b ----------------
__global__ __launch_bounds__(256) void k_gemm_pair(
    const u16* __restrict__ A0, const u16* __restrict__ A1, long aBS, int lda,
    const u16* __restrict__ B0, const u16* __restrict__ B1, int ldb,
    u16* __restrict__ C0, u16* __restrict__ C1, long cBS, int ldc,
    const float* __restrict__ g0, const float* __restrict__ be0,
    const float* __restrict__ g1, const float* __restrict__ be1, int K) {
    __shared__ u16 As[2][128 * 64];
    __shared__ u16 Bs[2][128 * 64];
    int z = blockIdx.z;
    int op = z >> 2, b = z & 3;
    const u16* Ab = (op ? A1 : A0) + (size_t)b * aBS;
    const u16* Bb = op ? B1 : B0;
    u16* Cb = (op ? C1 : C0) + (size_t)b * cBS;
    const float* gamma = op ? g1 : g0;
    const float* beta  = op ? be1 : be0;
    int m0 = blockIdx.x * 128, n0 = blockIdx.y * 128;
    int t = threadIdx.x;
    int lane = t & 63, wid = t >> 6;
    int wr = wid >> 1, wc = wid & 1;
    int li = lane & 15, lk = lane >> 4;

    f32x4 acc[4][4] = {};

    auto stage = [&](int k0, int buf) {
        #pragma unroll
        for (int j = 0; j < 4; j++) {
            int c = wid * 4 + j;
            u32 pl = (u32)c * 1024 + (u32)lane * 16;
            u32 r = pl >> 7;
            u32 q = (pl & 127) ^ ((r & 7) << 4);
            gll16(Ab + (size_t)(m0 + r) * lda + k0 + (q >> 1), &As[buf][0] + (c << 9));
            gll16(Bb + (size_t)(n0 + r) * ldb + k0 + (q >> 1), &Bs[buf][0] + (c << 9));
        }
    };

    const int nk = K >> 6;
    stage(0, 0);

    for (int kst = 0; kst < nk; kst++) {
        int cur = kst & 1;
        if (kst + 1 < nk) {
            stage((kst + 1) << 6, cur ^ 1);
            asm volatile("s_waitcnt vmcnt(8)" ::: "memory");
        } else {
            asm volatile("s_waitcnt vmcnt(0)" ::: "memory");
        }
        __builtin_amdgcn_sched_barrier(0);
        __builtin_amdgcn_s_barrier();

        const char* AsB = (const char*)&As[cur][0];
        const char* BsB = (const char*)&Bs[cur][0];
        #pragma unroll
        for (int ks = 0; ks < 2; ks++) {
            bf16x8 af[4], bfr[4];
            #pragma unroll
            for (int mi = 0; mi < 4; mi++) {
                int r = wr * 64 + mi * 16 + li;
                u32 off = ((u32)(r * 128 + (ks * 32 + lk * 8) * 2)) ^ (((u32)(r & 7)) << 4);
                af[mi] = *reinterpret_cast<const bf16x8*>(AsB + off);
            }
            #pragma unroll
            for (int ni = 0; ni < 4; ni++) {
                int r = wc * 64 + ni * 16 + li;
                u32 off = ((u32)(r * 128 + (ks * 32 + lk * 8) * 2)) ^ (((u32)(r & 7)) << 4);
                bfr[ni] = *reinterpret_cast<const bf16x8*>(BsB + off);
            }
            #pragma unroll
            for (int mi = 0; mi < 4; mi++)
                #pragma unroll
                for (int ni = 0; ni < 4; ni++)
                    acc[mi][ni] = mfma16(af[mi], bfr[ni], acc[mi][ni]);
        }
        asm volatile("s_waitcnt lgkmcnt(0)" ::: "memory");
        __builtin_amdgcn_s_barrier();
    }
    #pragma unroll
    for (int mi = 0; mi < 4; mi++) {
        #pragma unroll
        for (int ni = 0; ni < 4; ni++) {
            #pragma unroll
            for (int r = 0; r < 4; r++) {
                int m = m0 + wr * 64 + mi * 16 + lk * 4 + r;
                int n = n0 + wc * 64 + ni * 16 + li;
                float v = acc[mi][ni][r];
                float y = v * gamma[n] + beta[n];
                y = fmaxf(y, 0.f);
                Cb[(size_t)m * ldc + n] = f2bf(y);
            }
        }
    }
}

// ---------------- flash attention v8 (round-15 exact) ----------------
__global__ __launch_bounds__(256, 2) void k_attn(const u16* __restrict__ Q, const u16* __restrict__ Kt,
                                                 const u16* __restrict__ V, u16* __restrict__ Op,
                                                 float2* __restrict__ ML) {
    __shared__ u16 Ks[2][32 * 256];
    __shared__ u16 Vs[2][256 * 32];
    int wg = blockIdx.x;
    int bs = wg & 15, qt = wg >> 4;
    int b = bs >> 2, sp = bs & 3;
    int n0 = qt * 128;
    int k0 = sp * 1024;
    const size_t S = (size_t)4096 * 256;
    const u16* Qb = Q + (size_t)b * S + (size_t)n0 * 256;
    const u16* Kb = Kt + (size_t)b * S + (size_t)k0 * 256;
    const u16* Vb = V + (size_t)b * S + k0;
    int t = threadIdx.x;
    int lane = t & 63, wid = t >> 6;
    int li = lane & 15, lk = lane >> 4;
    int qw = wid * 32;

    bf16x8 qf[2][8];
    #pragma unroll
    for (int fq = 0; fq < 2; fq++)
        #pragma unroll
        for (int kc = 0; kc < 8; kc++)
            qf[fq][kc] = *reinterpret_cast<const bf16x8*>(Qb + (size_t)(qw + fq * 16 + li) * 256 + kc * 32 + lk * 8);

    f32x4 acc[2][16] = {};
    float M[2] = {-1e30f, -1e30f};
    float L[2] = {0.f, 0.f};
    const float SCL = 0.0625f * 1.44269504088896f;

    auto stage = [&](int kt, int buf) {
        const u16* Kp = Kb + (size_t)kt * 32 * 256;
        const u16* Vp = Vb + kt * 32;
        u16* Kd = &Ks[buf][0];
        u16* Vd = &Vs[buf][0];
        #pragma unroll
        for (int j = 0; j < 4; j++) {
            int c = wid * 4 + j;
            u32 pl = (u32)c * 1024 + (u32)lane * 16;
            u32 krow = pl >> 9;
            u32 kq = (pl & 511) ^ ((krow & 7) << 4);
            gll16(Kp + krow * 256 + (kq >> 1), Kd + (c << 9));
            u32 vcc = pl >> 6;
            u32 vq = (pl & 63) ^ (((vcc >> 1) & 3) << 4);
            gll16(Vp + (size_t)vcc * 4096 + (vq >> 1), Vd + (c << 9));
        }
    };

    stage(0, 0);

    for (int kt = 0; kt < 32; kt++) {
        int cur = kt & 1;
        if (kt + 1 < 32) {
            stage(kt + 1, cur ^ 1);
            asm volatile("s_waitcnt vmcnt(8)" ::: "memory");
        } else {
            asm volatile("s_waitcnt vmcnt(0)" ::: "memory");
        }
        __builtin_amdgcn_sched_barrier(0);
        __builtin_amdgcn_s_barrier();

        const char* KsB = (const char*)&Ks[cur][0];
        const char* VsB = (const char*)&Vs[cur][0];

        __builtin_amdgcn_s_setprio(1);
        f32x4 sf[2][2] = {};
        #pragma unroll
        for (int mk = 0; mk < 2; mk++) {
            #pragma unroll
            for (int kc = 0; kc < 8; kc++) {
                int row = mk * 16 + li;
                u32 off = (u32)(row * 512) + (((u32)(kc * 64 + lk * 16)) ^ (((u32)(row & 7)) << 4));
                bf16x8 kb = *reinterpret_cast<const bf16x8*>(KsB + off);
                sf[mk][0] = mfma16(kb, qf[0][kc], sf[mk][0]);
                sf[mk][1] = mfma16(kb, qf[1][kc], sf[mk][1]);
            }
        }
        __builtin_amdgcn_s_setprio(0);

        float lm[2];
        #pragma unroll
        for (int fq = 0; fq < 2; fq++) {
            lm[fq] = fmaxf(fmaxf(fmaxf(sf[0][fq][0], sf[0][fq][1]), fmaxf(sf[0][fq][2], sf[0][fq][3])),
                           fmaxf(fmaxf(sf[1][fq][0], sf[1][fq][1]), fmaxf(sf[1][fq][2], sf[1][fq][3]))) * SCL;
        }
        bool ok = (lm[0] <= M[0] + 24.f) && (lm[1] <= M[1] + 24.f);
        if (!__all(ok ? 1 : 0)) {
            #pragma unroll
            for (int fq = 0; fq < 2; fq++) {
                float mx = lm[fq];
                mx = fmaxf(mx, __shfl_xor(mx, 16));
                mx = fmaxf(mx, __shfl_xor(mx, 32));
                float nM = fmaxf(M[fq], mx);
                float rs = exp2f(M[fq] - nM);
                L[fq] *= rs; M[fq] = nM;
                #pragma unroll
                for (int ct = 0; ct < 16; ct++) {
                    acc[fq][ct][0] *= rs; acc[fq][ct][1] *= rs;
                    acc[fq][ct][2] *= rs; acc[fq][ct][3] *= rs;
                }
            }
        }

        bf16x8 pb[2];
        #pragma unroll
        for (int fq = 0; fq < 2; fq++) {
            float p00 = exp2f(sf[0][fq][0] * SCL - M[fq]);
            float p01 = exp2f(sf[0][fq][1] * SCL - M[fq]);
            float p02 = exp2f(sf[0][fq][2] * SCL - M[fq]);
            float p03 = exp2f(sf[0][fq][3] * SCL - M[fq]);
            float p10 = exp2f(sf[1][fq][0] * SCL - M[fq]);
            float p11 = exp2f(sf[1][fq][1] * SCL - M[fq]);
            float p12 = exp2f(sf[1][fq][2] * SCL - M[fq]);
            float p13 = exp2f(sf[1][fq][3] * SCL - M[fq]);
            L[fq] += ((p00 + p01) + (p02 + p03)) + ((p10 + p11) + (p12 + p13));
            BF8 pw;
            pw.u.x = cvtpk(p00, p01);
            pw.u.y = cvtpk(p02, p03);
            pw.u.z = cvtpk(p10, p11);
            pw.u.w = cvtpk(p12, p13);
            pb[fq] = pw.v;
        }

        __builtin_amdgcn_s_setprio(1);
        #pragma unroll
        for (int ct = 0; ct < 16; ct++) {
            int vr = ct * 16 + li;
            u32 sw = ((u32)((vr >> 1) & 3)) << 4;
            u32 lo = (u32)(vr * 64) + (((u32)(lk * 8)) ^ sw);
            u32 hi = (u32)(vr * 64) + (((u32)(32 + lk * 8)) ^ sw);
            BF8 va;
            *reinterpret_cast<uint2*>(&va.u.x) = *reinterpret_cast<const uint2*>(VsB + lo);
            *reinterpret_cast<uint2*>(&va.u.z) = *reinterpret_cast<const uint2*>(VsB + hi);
            acc[0][ct] = mfma16(va.v, pb[0], acc[0][ct]);
            acc[1][ct] = mfma16(va.v, pb[1], acc[1][ct]);
        }
        __builtin_amdgcn_s_setprio(0);
        asm volatile("s_waitcnt lgkmcnt(0)" ::: "memory");
        __builtin_amdgcn_s_barrier();
    }

    #pragma unroll
    for (int fq = 0; fq < 2; fq++) {
        L[fq] += __shfl_xor(L[fq], 16);
        L[fq] += __shfl_xor(L[fq], 32);
    }

    size_t obase = (size_t)(sp * 4 + b) * 4096 + n0;
    #pragma unroll
    for (int fq = 0; fq < 2; fq++) {
        int q = qw + fq * 16 + li;
        #pragma unroll
        for (int ct = 0; ct < 16; ct++) {
            uint2 ow;
            ow.x = cvtpk(acc[fq][ct][0], acc[fq][ct][1]);
            ow.y = cvtpk(acc[fq][ct][2], acc[fq][ct][3]);
            *reinterpret_cast<uint2*>(&Op[(obase + q) * 256 + ct * 16 + lk * 4]) = ow;
        }
    }
    if (lk == 0) {
        #pragma unroll
        for (int fq = 0; fq < 2; fq++) {
            float2 v; v.x = M[fq]; v.y = L[fq];
            ML[obase + qw + fq * 16 + li] = v;
        }
    }
}

// ---------------- merge split-KV partials -> ctx bf16 (vectorized: 4 q/block, 4 ch/thread) --------
__global__ __launch_bounds__(256) void k_merge(const u16* __restrict__ Op, const float2* __restrict__ ML,
                                               u16* __restrict__ ctx) {
    int wg = blockIdx.x;               // 4096 = 4b x 1024 q-groups
    int t = threadIdx.x;
    int b = wg >> 10;
    int q = (wg & 1023) * 4 + (t >> 6);
    int c4 = (t & 63) * 4;
    float2 ml[4];
    float Mx = -1e30f;
    #pragma unroll
    for (int s = 0; s < 4; s++) { ml[s] = ML[((size_t)(s * 4 + b) << 12) + q]; Mx = fmaxf(Mx, ml[s].x); }
    float Lt = 0.f, w[4];
    #pragma unroll
    for (int s = 0; s < 4; s++) { w[s] = exp2f(ml[s].x - Mx); Lt += ml[s].y * w[s]; }
    float inv = 1.f / Lt;
    float o0 = 0.f, o1 = 0.f, o2 = 0.f, o3 = 0.f;
    #pragma unroll
    for (int s = 0; s < 4; s++) {
        uint2 v = *reinterpret_cast<const uint2*>(&Op[(((size_t)(s * 4 + b) << 12) + q) * 256 + c4]);
        o0 += w[s] * bf2f((u16)(v.x & 0xFFFFu));
        o1 += w[s] * bf2f((u16)(v.x >> 16));
        o2 += w[s] * bf2f((u16)(v.y & 0xFFFFu));
        o3 += w[s] * bf2f((u16)(v.y >> 16));
    }
    uint2 ow;
    ow.x = cvtpk(o0 * inv, o1 * inv);
    ow.y = cvtpk(o2 * inv, o3 * inv);
    *reinterpret_cast<uint2*>(&ctx[(((size_t)b << 12) + q) * 256 + c4]) = ow;
}

extern "C" void kernel_launch(void* const* d_in, const int* in_sizes, int n_in,
                              void* d_out, int out_size, void* d_ws, size_t ws_size,
                              hipStream_t stream) {
    const void* x   = d_in[0];
    const void* qW1 = d_in[1];  const void* qg1 = d_in[2];  const void* qb1 = d_in[3];
    const void* qW2 = d_in[4];  const void* qg2 = d_in[5];  const void* qb2 = d_in[6];
    const void* kW1 = d_in[7];  const void* kg1 = d_in[8];  const void* kb1 = d_in[9];
    const void* kW2 = d_in[10]; const void* kg2 = d_in[11]; const void* kb2 = d_in[12];
    const void* vW  = d_in[13]; const void* vg  = d_in[14]; const void* vb  = d_in[15];
    const void* oW  = d_in[16]; const void* og  = d_in[17]; const void* ob  = d_in[18];

    char* ws = (char*)d_ws;
    int*   dflag = (int*)ws;
    float* xg = (float*)(ws + 4096);
    float* ck = (float*)(ws + 16384);
    float* cv = (float*)(ws + 20480);
    float* pg = (float*)(ws + 24576);
    u16* wb = (u16*)(ws + 40960);
    u16* qW1b = wb;
    u16* qW2b = wb + 131072;
    u16* kW1b = wb + 196608;
    u16* kW2b = wb + 327680;
    u16* vWb  = wb + 393216;
    u16* oWb  = wb + 524288;
    float* partials = (float*)(ws + 0x180000); // 512KB
    float2* mlBuf = (float2*)(ws + 0x200000);  // 512KB
    const size_t S = (size_t)4096 * 256;
    const size_t SLOT = 4 * S;
    u16* s0 = (u16*)(ws + 0x280000);
    u16* s1 = s0 + SLOT;
    u16* s2 = s1 + SLOT;
    u16* s3 = s2 + SLOT;
    u16* xT = (u16*)d_out;
    u16* k1buf = (u16*)d_out + 8388608;
    u16* opart = (u16*)d_out;
    u16* ctxBuf = s1;                          // ctx into s1 (Q dead after attn)

    k_detect<<<1, 256, 0, stream>>>((const u32*)x, dflag);
    k_xpose<<<dim3(64, 8, 4), 256, 0, stream>>>(x, dflag, xT, partials);
    k_mean2<<<8, 256, 0, stream>>>(partials, xg);
    k_consts<<<1024, 64, 0, stream>>>(kW1, vW, dflag, xg, ck, cv);
    k_wpconv<<<2574, 256, 0, stream>>>(qW1, qW2, kW1, kW2, vW, oW,
                                       qg1, qb1, qg2, qb2, kg1, kb1, kg2, kb2,
                                       vg, vb, og, ob, dflag, wb, pg);

    const long XS = (long)4096 * 512;
    // fused q1 + k1 + v
    k_gemm_tri<<<dim3(32, 2, 12), 256, 0, stream>>>(xT, XS, qW1b, kW1b, vWb,
        s0, k1buf, s3, (long)S, pg, ck, cv);
    // fused q2 + k2
    k_gemm_pair<<<dim3(32, 2, 8), 256, 0, stream>>>(s0, k1buf, (long)S, 256,
        qW2b, kW2b, 256, s1, s2, (long)S, 256,
        pg + 512, pg + 768, pg + 1536, pg + 1792, 256);
    // attention (split-KV x4): Q(s1), K(s2), V(s3) -> partials in d_out, ML
    k_attn<<<512, 256, 0, stream>>>(s1, s2, s3, opart, mlBuf);
    // merge -> ctx (s1)
    k_merge<<<4096, 256, 0, stream>>>(opart, mlBuf, ctxBuf);
    // out projection -> d_out as f32 [B][512][4096]
    k_gemm_bt<true, float><<<dim3(4, 32, 4), 256, 0, stream>>>(oWb, 0, 256, ctxBuf, (long)S, 256,
        (float*)d_out, (long)512 * 4096, 4096, pg + 2560, pg + 3072, nullptr, 0, 256);
}